// Round 3
// baseline (857.548 us; speedup 1.0000x reference)
//
#include <hip/hip_runtime.h>
#include <stdint.h>
#include <math.h>

#define N_NODES 50000
#define N_EDGES 800000
#define D 128
#define N_GRAPHS 16
#define NT 32          // nodes per GEMM block
#define ZSTRIDE 260    // 256 feats padded; float4-aligned rows, stride not multiple of 32 banks
#define PCH 512        // nodes per pool block
#define SCAN_BLOCKS 196

__device__ __forceinline__ float leaky(float y){ return y > 0.f ? y : 0.01f * y; }

// monotonic float->uint encoding for atomic max; 0 is an impossible code (marker for "empty")
__device__ __forceinline__ unsigned fenc(float f){
    unsigned u = __float_as_uint(f);
    return (f >= 0.f) ? (u | 0x80000000u) : ~u;
}
__device__ __forceinline__ float fdec(unsigned e){
    return (e & 0x80000000u) ? __uint_as_float(e & 0x7fffffffu) : __uint_as_float(~e);
}

// bf16 pack/unpack (round-to-nearest-even)
__device__ __forceinline__ unsigned short f2bf(float f){
    unsigned u = __float_as_uint(f);
    u += 0x7fffu + ((u >> 16) & 1u);
    return (unsigned short)(u >> 16);
}
__device__ __forceinline__ float bf2f(unsigned short s){
    return __uint_as_float(((unsigned)s) << 16);
}

// ---------------- init (replaces hipMemsetAsync) ----------------
__global__ __launch_bounds__(256) void k_init(int* __restrict__ deg, unsigned* __restrict__ xg){
    int i = blockIdx.x * 256 + threadIdx.x;
    if (i < N_NODES) deg[i] = 0;
    if (i < N_GRAPHS * D) xg[i] = 0u;
}

// ---------------- CSR build ----------------
__global__ __launch_bounds__(256) void k_hist(const int* __restrict__ dst, int* __restrict__ deg){
    int e = blockIdx.x * 256 + threadIdx.x;
    if (e < N_EDGES) atomicAdd(&deg[dst[e]], 1);
}

__global__ __launch_bounds__(256) void k_scan1(const int* __restrict__ deg, int* __restrict__ bsum){
    __shared__ int sh[256];
    int i = blockIdx.x * 256 + threadIdx.x;
    sh[threadIdx.x] = (i < N_NODES) ? deg[i] : 0;
    __syncthreads();
    for (int s = 128; s > 0; s >>= 1){
        if (threadIdx.x < s) sh[threadIdx.x] += sh[threadIdx.x + s];
        __syncthreads();
    }
    if (threadIdx.x == 0) bsum[blockIdx.x] = sh[0];
}

__global__ __launch_bounds__(256) void k_scan2(const int* __restrict__ bsum, int* __restrict__ bbase){
    __shared__ int sh[256];
    int t = threadIdx.x;
    int v = (t < SCAN_BLOCKS) ? bsum[t] : 0;
    sh[t] = v;
    __syncthreads();
    for (int d = 1; d < 256; d <<= 1){
        int tv = (t >= d) ? sh[t - d] : 0;
        __syncthreads();
        sh[t] += tv;
        __syncthreads();
    }
    if (t < SCAN_BLOCKS) bbase[t] = sh[t] - v;   // exclusive
}

__global__ __launch_bounds__(256) void k_scan3(const int* __restrict__ deg, const int* __restrict__ bbase,
                                               int* __restrict__ off, int* __restrict__ cursor){
    __shared__ int sh[256];
    int t = threadIdx.x;
    int i = blockIdx.x * 256 + t;
    int v = (i < N_NODES) ? deg[i] : 0;
    sh[t] = v;
    __syncthreads();
    for (int d = 1; d < 256; d <<= 1){
        int tv = (t >= d) ? sh[t - d] : 0;
        __syncthreads();
        sh[t] += tv;
        __syncthreads();
    }
    if (i < N_NODES){
        int e = bbase[blockIdx.x] + sh[t] - v;
        off[i] = e;
        cursor[i] = e;
    }
}

__global__ __launch_bounds__(256) void k_fill(const int* __restrict__ src, const int* __restrict__ dst,
                                              int* __restrict__ cursor, int* __restrict__ csr){
    int e = blockIdx.x * 256 + threadIdx.x;
    if (e < N_EDGES){
        int d = dst[e];
        int p = atomicAdd(&cursor[d], 1);
        csr[p] = src[e];
    }
}

// ---------------- per-step: segment-max aggregate (gather form, bf16 out) ----------------
// one wave per node; lane l covers feats 2l, 2l+1
__global__ __launch_bounds__(256) void k_agg(const float* __restrict__ h, const int* __restrict__ off,
                                             const int* __restrict__ deg, const int* __restrict__ csr,
                                             unsigned short* __restrict__ aggb){
    int wave = blockIdx.x * 4 + (threadIdx.x >> 6);
    int lane = threadIdx.x & 63;
    if (wave >= N_NODES) return;
    int n = deg[wave];
    int base = off[wave];
    float ax = -INFINITY, ay = -INFINITY;
    int i = 0;
    for (; i + 2 <= n; i += 2){        // 2-deep ILP on the gather chain
        int s0 = csr[base + i];
        int s1 = csr[base + i + 1];
        float2 v0 = *(const float2*)&h[(size_t)s0 * D + 2 * lane];
        float2 v1 = *(const float2*)&h[(size_t)s1 * D + 2 * lane];
        ax = fmaxf(ax, fmaxf(v0.x, v1.x));
        ay = fmaxf(ay, fmaxf(v0.y, v1.y));
    }
    if (i < n){
        int s0 = csr[base + i];
        float2 v0 = *(const float2*)&h[(size_t)s0 * D + 2 * lane];
        ax = fmaxf(ax, v0.x);
        ay = fmaxf(ay, v0.y);
    }
    if (n == 0){ ax = 0.f; ay = 0.f; }
    ushort2 r; r.x = f2bf(ax); r.y = f2bf(ay);
    *(ushort2*)&aggb[(size_t)wave * D + 2 * lane] = r;
}

// ---------------- per-step: fused [h|agg] @ W + b, leaky, skip, in-place ----------------
__global__ __launch_bounds__(256) void k_gemm(const float* __restrict__ hin, const unsigned short* __restrict__ aggb,
                                              const float* __restrict__ W, const float* __restrict__ b,
                                              float* __restrict__ hout, int add_skip){
    __shared__ float zt[NT * ZSTRIDE];
    int tid = threadIdx.x;
    int nb = blockIdx.x * NT;

    // stage z = [h | agg] tile: 32 nodes x 256 feats
    #pragma unroll
    for (int j = 0; j < 8; j++){
        int idx = j * 256 + tid;        // 0..2047 4-feat slots
        int n = idx >> 6;               // 0..31
        int q = idx & 63;               // quad 0..63 -> feat 4q
        int node = nb + n;
        float4 v;
        if (node < N_NODES){
            if (q < 32){
                v = *(const float4*)&hin[(size_t)node * D + 4 * q];
            } else {
                ushort4 a4 = *(const ushort4*)&aggb[(size_t)node * D + 4 * (q - 32)];
                v.x = bf2f(a4.x); v.y = bf2f(a4.y); v.z = bf2f(a4.z); v.w = bf2f(a4.w);
            }
        } else {
            v = make_float4(0.f, 0.f, 0.f, 0.f);
        }
        *(float4*)&zt[n * ZSTRIDE + 4 * q] = v;
    }
    __syncthreads();

    int og = tid & 31;     // output quad -> outputs og*4..+3
    int ng = tid >> 5;     // node group -> nodes ng*4..+3
    float acc[4][4];
    #pragma unroll
    for (int i = 0; i < 4; i++)
        #pragma unroll
        for (int j = 0; j < 4; j++) acc[i][j] = 0.f;

    const float* zrow0 = &zt[(ng * 4 + 0) * ZSTRIDE];
    const float* zrow1 = &zt[(ng * 4 + 1) * ZSTRIDE];
    const float* zrow2 = &zt[(ng * 4 + 2) * ZSTRIDE];
    const float* zrow3 = &zt[(ng * 4 + 3) * ZSTRIDE];

    #pragma unroll 4
    for (int k = 0; k < 2 * D; k++){
        float4 w4 = *(const float4*)&W[(size_t)k * D + og * 4];
        float z0 = zrow0[k], z1 = zrow1[k], z2 = zrow2[k], z3 = zrow3[k];
        acc[0][0] = fmaf(z0, w4.x, acc[0][0]); acc[0][1] = fmaf(z0, w4.y, acc[0][1]);
        acc[0][2] = fmaf(z0, w4.z, acc[0][2]); acc[0][3] = fmaf(z0, w4.w, acc[0][3]);
        acc[1][0] = fmaf(z1, w4.x, acc[1][0]); acc[1][1] = fmaf(z1, w4.y, acc[1][1]);
        acc[1][2] = fmaf(z1, w4.z, acc[1][2]); acc[1][3] = fmaf(z1, w4.w, acc[1][3]);
        acc[2][0] = fmaf(z2, w4.x, acc[2][0]); acc[2][1] = fmaf(z2, w4.y, acc[2][1]);
        acc[2][2] = fmaf(z2, w4.z, acc[2][2]); acc[2][3] = fmaf(z2, w4.w, acc[2][3]);
        acc[3][0] = fmaf(z3, w4.x, acc[3][0]); acc[3][1] = fmaf(z3, w4.y, acc[3][1]);
        acc[3][2] = fmaf(z3, w4.z, acc[3][2]); acc[3][3] = fmaf(z3, w4.w, acc[3][3]);
    }

    float4 b4 = *(const float4*)&b[og * 4];
    #pragma unroll
    for (int i = 0; i < 4; i++){
        int nloc = ng * 4 + i;
        int node = nb + nloc;
        if (node < N_NODES){
            float y0 = leaky(acc[i][0] + b4.x);
            float y1 = leaky(acc[i][1] + b4.y);
            float y2 = leaky(acc[i][2] + b4.z);
            float y3 = leaky(acc[i][3] + b4.w);
            if (add_skip){
                const float* hold = &zt[nloc * ZSTRIDE + og * 4];  // first 128 of z == old h
                y0 += hold[0]; y1 += hold[1]; y2 += hold[2]; y3 += hold[3];
            }
            float4 r; r.x = y0; r.y = y1; r.z = y2; r.w = y3;
            *(float4*)&hout[(size_t)node * D + og * 4] = r;
        }
    }
}

// ---------------- global max-pool per graph (batch_ind sorted, int32) ----------------
__global__ __launch_bounds__(128) void k_pool(const float* __restrict__ h, const int* __restrict__ batch,
                                              unsigned* __restrict__ xg){
    __shared__ int bsh[PCH];
    int n0 = blockIdx.x * PCH;
    int n1 = min(n0 + PCH, N_NODES);
    int cnt = n1 - n0;
    for (int i = threadIdx.x; i < cnt; i += 128) bsh[i] = batch[n0 + i];
    __syncthreads();
    int f = threadIdx.x;
    int curg = bsh[0];
    float m = -INFINITY;
    for (int i = 0; i < cnt; i++){
        int g = bsh[i];
        if (g != curg){               // block-uniform branch
            atomicMax(&xg[curg * D + f], fenc(m));
            curg = g;
            m = -INFINITY;
        }
        m = fmaxf(m, h[(size_t)(n0 + i) * D + f]);
    }
    atomicMax(&xg[curg * D + f], fenc(m));
}

// ---------------- head: leaky(xg @ wg[:128] + bg) ----------------
__global__ __launch_bounds__(256) void k_final(const unsigned* __restrict__ xg_enc, const float* __restrict__ wg,
                                               const float* __restrict__ bg, float* __restrict__ out){
    __shared__ float xs[N_GRAPHS * D];
    int tid = threadIdx.x;
    for (int i = tid; i < N_GRAPHS * D; i += 256){
        unsigned e = xg_enc[i];
        xs[i] = (e == 0u) ? 0.f : fdec(e);   // empty graph -> 0
    }
    __syncthreads();
    int g = tid >> 4;              // 0..15
    int j0 = (tid & 15) * 8;       // 8 consecutive outputs
    float acc[8];
    #pragma unroll
    for (int j = 0; j < 8; j++) acc[j] = 0.f;
    for (int k = 0; k < D; k++){
        float xv = xs[g * D + k];
        const float* wr = &wg[(size_t)k * D + j0];
        #pragma unroll
        for (int j = 0; j < 8; j++) acc[j] = fmaf(xv, wr[j], acc[j]);
    }
    float* orow = &out[(size_t)N_NODES * D + g * D + j0];
    #pragma unroll
    for (int j = 0; j < 8; j++) orow[j] = leaky(acc[j] + bg[j0 + j]);  // xg_old == 0
}

extern "C" void kernel_launch(void* const* d_in, const int* in_sizes, int n_in,
                              void* d_out, int out_size, void* d_ws, size_t ws_size,
                              hipStream_t stream){
    const float* x = (const float*)d_in[0];
    const int* eidx  = (const int*)d_in[1];   // harness converts integer inputs to int32
    const int* batch = (const int*)d_in[2];   // int32
    const float* w[4]  = {(const float*)d_in[4], (const float*)d_in[6], (const float*)d_in[8], (const float*)d_in[10]};
    const float* bb[4] = {(const float*)d_in[5], (const float*)d_in[7], (const float*)d_in[9], (const float*)d_in[11]};
    const float* wg = (const float*)d_in[12];
    const float* bg = (const float*)d_in[13];
    const int* esrc = eidx;            // edge_index[0] = src
    const int* edst = eidx + N_EDGES;  // edge_index[1] = dst

    // workspace layout (total ~16.6 MB)
    char* ws = (char*)d_ws;
    int* deg    = (int*)ws;       ws += 50048 * 4;
    int* off    = (int*)ws;       ws += 50048 * 4;
    int* cursor = (int*)ws;       ws += 50048 * 4;
    int* bsum   = (int*)ws;       ws += 256 * 4;
    int* bbase  = (int*)ws;       ws += 256 * 4;
    int* csr    = (int*)ws;       ws += N_EDGES * 4;
    unsigned* xg_enc = (unsigned*)ws; ws += N_GRAPHS * D * 4;
    unsigned short* aggb = (unsigned short*)(((uintptr_t)ws + 255) & ~(uintptr_t)255); // 12.8 MB
    float* h    = (float*)d_out;   // h lives directly in the output buffer

    hipMemcpyAsync(h, x, (size_t)N_NODES * D * 4, hipMemcpyDeviceToDevice, stream);

    k_init <<<SCAN_BLOCKS, 256, 0, stream>>>(deg, xg_enc);
    k_hist <<<(N_EDGES + 255) / 256, 256, 0, stream>>>(edst, deg);
    k_scan1<<<SCAN_BLOCKS, 256, 0, stream>>>(deg, bsum);
    k_scan2<<<1, 256, 0, stream>>>(bsum, bbase);
    k_scan3<<<SCAN_BLOCKS, 256, 0, stream>>>(deg, bbase, off, cursor);
    k_fill <<<(N_EDGES + 255) / 256, 256, 0, stream>>>(esrc, edst, cursor, csr);

    for (int s = 0; s < 4; s++){
        k_agg <<<(N_NODES + 3) / 4, 256, 0, stream>>>(h, off, deg, csr, aggb);
        k_gemm<<<(N_NODES + NT - 1) / NT, 256, 0, stream>>>(h, aggb, w[s], bb[s], h, s > 0);
    }

    k_pool <<<(N_NODES + PCH - 1) / PCH, 128, 0, stream>>>(h, batch, xg_enc);
    k_final<<<1, 256, 0, stream>>>(xg_enc, wg, bg, (float*)d_out);
}

// Round 4
// 689.098 us; speedup vs baseline: 1.2444x; 1.2444x over previous
//
#include <hip/hip_runtime.h>
#include <stdint.h>
#include <math.h>

#define N_NODES 50000
#define N_EDGES 800000
#define D 128
#define N_GRAPHS 16
#define NT 32          // nodes per GEMM block
#define ZSTRIDE 260    // 256 feats padded; float4-aligned rows, stride not multiple of 32 banks
#define PBLK 128       // nodes per pool block
#define PSL 16         // nodes per pool slice (PBLK/8)
#define SCAN_BLOCKS 196

__device__ __forceinline__ float leaky(float y){ return y > 0.f ? y : 0.01f * y; }

// monotonic float->uint encoding for atomic max; 0 is an impossible code (marker for "empty")
__device__ __forceinline__ unsigned fenc(float f){
    unsigned u = __float_as_uint(f);
    return (f >= 0.f) ? (u | 0x80000000u) : ~u;
}
__device__ __forceinline__ float fdec(unsigned e){
    return (e & 0x80000000u) ? __uint_as_float(e & 0x7fffffffu) : __uint_as_float(~e);
}

// bf16 pack/unpack (round-to-nearest-even)
__device__ __forceinline__ unsigned short f2bf(float f){
    unsigned u = __float_as_uint(f);
    u += 0x7fffu + ((u >> 16) & 1u);
    return (unsigned short)(u >> 16);
}
__device__ __forceinline__ float bf2f(unsigned short s){
    return __uint_as_float(((unsigned)s) << 16);
}

__device__ __forceinline__ float4 max4(float4 a, float4 b){
    float4 r;
    r.x = fmaxf(a.x, b.x); r.y = fmaxf(a.y, b.y);
    r.z = fmaxf(a.z, b.z); r.w = fmaxf(a.w, b.w);
    return r;
}

// ---------------- init ----------------
__global__ __launch_bounds__(256) void k_init(int* __restrict__ deg, unsigned* __restrict__ xg){
    int i = blockIdx.x * 256 + threadIdx.x;
    if (i < N_NODES) deg[i] = 0;
    if (i < N_GRAPHS * D) xg[i] = 0u;
}

// ---------------- CSR build ----------------
__global__ __launch_bounds__(256) void k_hist(const int* __restrict__ dst, int* __restrict__ deg){
    int e = blockIdx.x * 256 + threadIdx.x;
    if (e < N_EDGES) atomicAdd(&deg[dst[e]], 1);
}

__global__ __launch_bounds__(256) void k_scan1(const int* __restrict__ deg, int* __restrict__ bsum){
    __shared__ int sh[256];
    int i = blockIdx.x * 256 + threadIdx.x;
    sh[threadIdx.x] = (i < N_NODES) ? deg[i] : 0;
    __syncthreads();
    for (int s = 128; s > 0; s >>= 1){
        if (threadIdx.x < s) sh[threadIdx.x] += sh[threadIdx.x + s];
        __syncthreads();
    }
    if (threadIdx.x == 0) bsum[blockIdx.x] = sh[0];
}

__global__ __launch_bounds__(256) void k_scan2(const int* __restrict__ bsum, int* __restrict__ bbase){
    __shared__ int sh[256];
    int t = threadIdx.x;
    int v = (t < SCAN_BLOCKS) ? bsum[t] : 0;
    sh[t] = v;
    __syncthreads();
    for (int d = 1; d < 256; d <<= 1){
        int tv = (t >= d) ? sh[t - d] : 0;
        __syncthreads();
        sh[t] += tv;
        __syncthreads();
    }
    if (t < SCAN_BLOCKS) bbase[t] = sh[t] - v;   // exclusive
}

__global__ __launch_bounds__(256) void k_scan3(const int* __restrict__ deg, const int* __restrict__ bbase,
                                               int* __restrict__ off, int* __restrict__ cursor){
    __shared__ int sh[256];
    int t = threadIdx.x;
    int i = blockIdx.x * 256 + t;
    int v = (i < N_NODES) ? deg[i] : 0;
    sh[t] = v;
    __syncthreads();
    for (int d = 1; d < 256; d <<= 1){
        int tv = (t >= d) ? sh[t - d] : 0;
        __syncthreads();
        sh[t] += tv;
        __syncthreads();
    }
    if (i < N_NODES){
        int e = bbase[blockIdx.x] + sh[t] - v;
        off[i] = e;
        cursor[i] = e;
    }
}

__global__ __launch_bounds__(256) void k_fill(const int* __restrict__ src, const int* __restrict__ dst,
                                              int* __restrict__ cursor, int* __restrict__ csr){
    int e = blockIdx.x * 256 + threadIdx.x;
    if (e < N_EDGES){
        int d = dst[e];
        int p = atomicAdd(&cursor[d], 1);
        csr[p] = src[e];
    }
}

// ---------------- per-step: segment-max aggregate (gather, bf16 out) ----------------
// one wave per node; lane = (quad q, half hf). Lane loads float4 (feats 4q..4q+3);
// halves split the edge list -> 2 rows per wave-instruction; 8-edge unroll = 4 loads in flight.
__global__ __launch_bounds__(256) void k_agg(const float* __restrict__ h, const int* __restrict__ off,
                                             const int* __restrict__ deg, const int* __restrict__ csr,
                                             unsigned short* __restrict__ aggb){
    int node = blockIdx.x * 4 + (threadIdx.x >> 6);
    int lane = threadIdx.x & 63;
    if (node >= N_NODES) return;
    int q  = lane & 31;
    int hf = lane >> 5;
    int n = deg[node];
    int base = off[node];
    const float NEG = -INFINITY;
    float4 a0 = make_float4(NEG, NEG, NEG, NEG);
    float4 a1 = a0, a2 = a0, a3 = a0;
    int i = 0;
    for (; i + 8 <= n; i += 8){
        int b4 = base + i + 4 * hf;     // half hf takes edges i+4hf .. i+4hf+3
        int s0 = csr[b4 + 0];
        int s1 = csr[b4 + 1];
        int s2 = csr[b4 + 2];
        int s3 = csr[b4 + 3];
        float4 v0 = *(const float4*)&h[(size_t)s0 * D + 4 * q];
        float4 v1 = *(const float4*)&h[(size_t)s1 * D + 4 * q];
        float4 v2 = *(const float4*)&h[(size_t)s2 * D + 4 * q];
        float4 v3 = *(const float4*)&h[(size_t)s3 * D + 4 * q];
        a0 = max4(a0, v0); a1 = max4(a1, v1);
        a2 = max4(a2, v2); a3 = max4(a3, v3);
    }
    for (; i + 2 <= n; i += 2){         // pair tail: half hf takes edge i+hf
        int s0 = csr[base + i + hf];
        float4 v0 = *(const float4*)&h[(size_t)s0 * D + 4 * q];
        a0 = max4(a0, v0);
    }
    if (i < n && hf == 0){              // final single edge
        int s0 = csr[base + i];
        float4 v0 = *(const float4*)&h[(size_t)s0 * D + 4 * q];
        a1 = max4(a1, v0);
    }
    a0 = max4(max4(a0, a1), max4(a2, a3));
    // merge halves (lane ^ 32)
    float4 o;
    o.x = fmaxf(a0.x, __shfl_xor(a0.x, 32, 64));
    o.y = fmaxf(a0.y, __shfl_xor(a0.y, 32, 64));
    o.z = fmaxf(a0.z, __shfl_xor(a0.z, 32, 64));
    o.w = fmaxf(a0.w, __shfl_xor(a0.w, 32, 64));
    if (n == 0){ o = make_float4(0.f, 0.f, 0.f, 0.f); }
    if (hf == 0){
        ushort4 r;
        r.x = f2bf(o.x); r.y = f2bf(o.y); r.z = f2bf(o.z); r.w = f2bf(o.w);
        *(ushort4*)&aggb[(size_t)node * D + 4 * q] = r;
    }
}

// ---------------- per-step: fused [h|agg] @ W + b, leaky, skip, in-place ----------------
__global__ __launch_bounds__(256) void k_gemm(const float* __restrict__ hin, const unsigned short* __restrict__ aggb,
                                              const float* __restrict__ W, const float* __restrict__ b,
                                              float* __restrict__ hout, int add_skip){
    __shared__ float zt[NT * ZSTRIDE];
    int tid = threadIdx.x;
    int nb = blockIdx.x * NT;

    #pragma unroll
    for (int j = 0; j < 8; j++){
        int idx = j * 256 + tid;        // 0..2047 4-feat slots
        int n = idx >> 6;               // 0..31
        int q = idx & 63;               // quad 0..63 -> feat 4q
        int node = nb + n;
        float4 v;
        if (node < N_NODES){
            if (q < 32){
                v = *(const float4*)&hin[(size_t)node * D + 4 * q];
            } else {
                ushort4 a4 = *(const ushort4*)&aggb[(size_t)node * D + 4 * (q - 32)];
                v.x = bf2f(a4.x); v.y = bf2f(a4.y); v.z = bf2f(a4.z); v.w = bf2f(a4.w);
            }
        } else {
            v = make_float4(0.f, 0.f, 0.f, 0.f);
        }
        *(float4*)&zt[n * ZSTRIDE + 4 * q] = v;
    }
    __syncthreads();

    int og = tid & 31;     // output quad
    int ng = tid >> 5;     // node group
    float acc[4][4];
    #pragma unroll
    for (int i = 0; i < 4; i++)
        #pragma unroll
        for (int j = 0; j < 4; j++) acc[i][j] = 0.f;

    const float* zrow0 = &zt[(ng * 4 + 0) * ZSTRIDE];
    const float* zrow1 = &zt[(ng * 4 + 1) * ZSTRIDE];
    const float* zrow2 = &zt[(ng * 4 + 2) * ZSTRIDE];
    const float* zrow3 = &zt[(ng * 4 + 3) * ZSTRIDE];

    #pragma unroll 4
    for (int k = 0; k < 2 * D; k++){
        float4 w4 = *(const float4*)&W[(size_t)k * D + og * 4];
        float z0 = zrow0[k], z1 = zrow1[k], z2 = zrow2[k], z3 = zrow3[k];
        acc[0][0] = fmaf(z0, w4.x, acc[0][0]); acc[0][1] = fmaf(z0, w4.y, acc[0][1]);
        acc[0][2] = fmaf(z0, w4.z, acc[0][2]); acc[0][3] = fmaf(z0, w4.w, acc[0][3]);
        acc[1][0] = fmaf(z1, w4.x, acc[1][0]); acc[1][1] = fmaf(z1, w4.y, acc[1][1]);
        acc[1][2] = fmaf(z1, w4.z, acc[1][2]); acc[1][3] = fmaf(z1, w4.w, acc[1][3]);
        acc[2][0] = fmaf(z2, w4.x, acc[2][0]); acc[2][1] = fmaf(z2, w4.y, acc[2][1]);
        acc[2][2] = fmaf(z2, w4.z, acc[2][2]); acc[2][3] = fmaf(z2, w4.w, acc[2][3]);
        acc[3][0] = fmaf(z3, w4.x, acc[3][0]); acc[3][1] = fmaf(z3, w4.y, acc[3][1]);
        acc[3][2] = fmaf(z3, w4.z, acc[3][2]); acc[3][3] = fmaf(z3, w4.w, acc[3][3]);
    }

    float4 b4 = *(const float4*)&b[og * 4];
    #pragma unroll
    for (int i = 0; i < 4; i++){
        int nloc = ng * 4 + i;
        int node = nb + nloc;
        if (node < N_NODES){
            float y0 = leaky(acc[i][0] + b4.x);
            float y1 = leaky(acc[i][1] + b4.y);
            float y2 = leaky(acc[i][2] + b4.z);
            float y3 = leaky(acc[i][3] + b4.w);
            if (add_skip){
                const float* hold = &zt[nloc * ZSTRIDE + og * 4];
                y0 += hold[0]; y1 += hold[1]; y2 += hold[2]; y3 += hold[3];
            }
            float4 r; r.x = y0; r.y = y1; r.z = y2; r.w = y3;
            *(float4*)&hout[(size_t)node * D + og * 4] = r;
        }
    }
}

// ---------------- global max-pool per graph (batch sorted, int32) ----------------
// 256 threads: quad q = tid&31 (feats 4q..4q+3), slice s = tid>>5 (PSL nodes each).
// LDS pre-reduction for the (<=2 typical) graphs a 128-node block spans.
__global__ __launch_bounds__(256) void k_pool(const float* __restrict__ h, const int* __restrict__ batch,
                                              unsigned* __restrict__ xg){
    __shared__ unsigned lmax[2 * D];
    int tid = threadIdx.x;
    lmax[tid] = 0u;
    __syncthreads();

    int n0 = blockIdx.x * PBLK;
    int g0 = batch[n0];                 // block's first graph (n0 < N_NODES for all blocks)
    int q = tid & 31;
    int s = tid >> 5;
    int i0 = n0 + s * PSL;
    int i1 = min(i0 + PSL, N_NODES);

    if (i0 < N_NODES){
        const float NEG = -INFINITY;
        float4 m = make_float4(NEG, NEG, NEG, NEG);
        int curg = batch[i0];
        int i = i0;
        for (; i + 2 <= i1; i += 2){
            int ga = batch[i];
            int gb = batch[i + 1];
            float4 va = *(const float4*)&h[(size_t)i * D + 4 * q];
            float4 vb = *(const float4*)&h[(size_t)(i + 1) * D + 4 * q];
            if (ga != curg){
                int rel = curg - g0;
                unsigned* dst = (rel < 2) ? &lmax[rel * D + 4 * q] : &xg[curg * D + 4 * q];
                atomicMax(dst + 0, fenc(m.x)); atomicMax(dst + 1, fenc(m.y));
                atomicMax(dst + 2, fenc(m.z)); atomicMax(dst + 3, fenc(m.w));
                curg = ga; m = make_float4(NEG, NEG, NEG, NEG);
            }
            m = max4(m, va);
            if (gb != curg){
                int rel = curg - g0;
                unsigned* dst = (rel < 2) ? &lmax[rel * D + 4 * q] : &xg[curg * D + 4 * q];
                atomicMax(dst + 0, fenc(m.x)); atomicMax(dst + 1, fenc(m.y));
                atomicMax(dst + 2, fenc(m.z)); atomicMax(dst + 3, fenc(m.w));
                curg = gb; m = make_float4(NEG, NEG, NEG, NEG);
            }
            m = max4(m, vb);
        }
        if (i < i1){
            int ga = batch[i];
            float4 va = *(const float4*)&h[(size_t)i * D + 4 * q];
            if (ga != curg){
                int rel = curg - g0;
                unsigned* dst = (rel < 2) ? &lmax[rel * D + 4 * q] : &xg[curg * D + 4 * q];
                atomicMax(dst + 0, fenc(m.x)); atomicMax(dst + 1, fenc(m.y));
                atomicMax(dst + 2, fenc(m.z)); atomicMax(dst + 3, fenc(m.w));
                curg = ga; m = make_float4(NEG, NEG, NEG, NEG);
            }
            m = max4(m, va);
        }
        {   // final flush
            int rel = curg - g0;
            unsigned* dst = (rel < 2) ? &lmax[rel * D + 4 * q] : &xg[curg * D + 4 * q];
            atomicMax(dst + 0, fenc(m.x)); atomicMax(dst + 1, fenc(m.y));
            atomicMax(dst + 2, fenc(m.z)); atomicMax(dst + 3, fenc(m.w));
        }
    }
    __syncthreads();

    if (tid < D){
        unsigned e = lmax[tid];
        if (e) atomicMax(&xg[g0 * D + tid], e);
    } else {
        int f = tid - D;
        int g1 = g0 + 1;
        if (g1 < N_GRAPHS){
            unsigned e = lmax[D + f];
            if (e) atomicMax(&xg[g1 * D + f], e);
        }
    }
}

// ---------------- head: leaky(xg @ wg[:128] + bg) ----------------
__global__ __launch_bounds__(256) void k_final(const unsigned* __restrict__ xg_enc, const float* __restrict__ wg,
                                               const float* __restrict__ bg, float* __restrict__ out){
    __shared__ float xs[N_GRAPHS * D];
    int tid = threadIdx.x;
    for (int i = tid; i < N_GRAPHS * D; i += 256){
        unsigned e = xg_enc[i];
        xs[i] = (e == 0u) ? 0.f : fdec(e);   // empty graph -> 0
    }
    __syncthreads();
    int g = tid >> 4;
    int j0 = (tid & 15) * 8;
    float acc[8];
    #pragma unroll
    for (int j = 0; j < 8; j++) acc[j] = 0.f;
    for (int k = 0; k < D; k++){
        float xv = xs[g * D + k];
        const float* wr = &wg[(size_t)k * D + j0];
        #pragma unroll
        for (int j = 0; j < 8; j++) acc[j] = fmaf(xv, wr[j], acc[j]);
    }
    float* orow = &out[(size_t)N_NODES * D + g * D + j0];
    #pragma unroll
    for (int j = 0; j < 8; j++) orow[j] = leaky(acc[j] + bg[j0 + j]);
}

extern "C" void kernel_launch(void* const* d_in, const int* in_sizes, int n_in,
                              void* d_out, int out_size, void* d_ws, size_t ws_size,
                              hipStream_t stream){
    const float* x = (const float*)d_in[0];
    const int* eidx  = (const int*)d_in[1];   // harness converts integer inputs to int32
    const int* batch = (const int*)d_in[2];
    const float* w[4]  = {(const float*)d_in[4], (const float*)d_in[6], (const float*)d_in[8], (const float*)d_in[10]};
    const float* bb[4] = {(const float*)d_in[5], (const float*)d_in[7], (const float*)d_in[9], (const float*)d_in[11]};
    const float* wg = (const float*)d_in[12];
    const float* bg = (const float*)d_in[13];
    const int* esrc = eidx;
    const int* edst = eidx + N_EDGES;

    char* ws = (char*)d_ws;
    int* deg    = (int*)ws;       ws += 50048 * 4;
    int* off    = (int*)ws;       ws += 50048 * 4;
    int* cursor = (int*)ws;       ws += 50048 * 4;
    int* bsum   = (int*)ws;       ws += 256 * 4;
    int* bbase  = (int*)ws;       ws += 256 * 4;
    int* csr    = (int*)ws;       ws += N_EDGES * 4;
    unsigned* xg_enc = (unsigned*)ws; ws += N_GRAPHS * D * 4;
    unsigned short* aggb = (unsigned short*)(((uintptr_t)ws + 255) & ~(uintptr_t)255); // 12.8 MB
    float* h    = (float*)d_out;

    hipMemcpyAsync(h, x, (size_t)N_NODES * D * 4, hipMemcpyDeviceToDevice, stream);

    k_init <<<SCAN_BLOCKS, 256, 0, stream>>>(deg, xg_enc);
    k_hist <<<(N_EDGES + 255) / 256, 256, 0, stream>>>(edst, deg);
    k_scan1<<<SCAN_BLOCKS, 256, 0, stream>>>(deg, bsum);
    k_scan2<<<1, 256, 0, stream>>>(bsum, bbase);
    k_scan3<<<SCAN_BLOCKS, 256, 0, stream>>>(deg, bbase, off, cursor);
    k_fill <<<(N_EDGES + 255) / 256, 256, 0, stream>>>(esrc, edst, cursor, csr);

    for (int s = 0; s < 4; s++){
        k_agg <<<(N_NODES + 3) / 4, 256, 0, stream>>>(h, off, deg, csr, aggb);
        k_gemm<<<(N_NODES + NT - 1) / NT, 256, 0, stream>>>(h, aggb, w[s], bb[s], h, s > 0);
    }

    k_pool <<<(N_NODES + PBLK - 1) / PBLK, 256, 0, stream>>>(h, batch, xg_enc);
    k_final<<<1, 256, 0, stream>>>(xg_enc, wg, bg, (float*)d_out);
}

// Round 5
// 620.978 us; speedup vs baseline: 1.3810x; 1.1097x over previous
//
#include <hip/hip_runtime.h>
#include <stdint.h>
#include <math.h>

#define N_NODES 50000
#define N_EDGES 800000
#define D 128
#define N_GRAPHS 16
#define ZP 264         // LDS z-tile row pitch in bf16 elems (264*2B=528B=33*16 -> aligned, 2-way banks)
#define PBLK 128       // nodes per pool block
#define PSL 16         // nodes per pool slice
#define SCAN_BLOCKS 196

typedef __attribute__((ext_vector_type(8))) short bf16x8;   // 8 bf16 (4 VGPRs)
typedef __attribute__((ext_vector_type(4))) float f32x4;

__device__ __forceinline__ float leaky(float y){ return y > 0.f ? y : 0.01f * y; }

// monotonic float->uint encoding for atomic max; 0 = "empty" marker
__device__ __forceinline__ unsigned fenc(float f){
    unsigned u = __float_as_uint(f);
    return (f >= 0.f) ? (u | 0x80000000u) : ~u;
}
__device__ __forceinline__ float fdec(unsigned e){
    return (e & 0x80000000u) ? __uint_as_float(e & 0x7fffffffu) : __uint_as_float(~e);
}

// bf16 pack/unpack (round-to-nearest-even)
__device__ __forceinline__ unsigned short f2bf(float f){
    unsigned u = __float_as_uint(f);
    u += 0x7fffu + ((u >> 16) & 1u);
    return (unsigned short)(u >> 16);
}
__device__ __forceinline__ float bf2f(unsigned short s){
    return __uint_as_float(((unsigned)s) << 16);
}

__device__ __forceinline__ float4 max4(float4 a, float4 b){
    float4 r;
    r.x = fmaxf(a.x, b.x); r.y = fmaxf(a.y, b.y);
    r.z = fmaxf(a.z, b.z); r.w = fmaxf(a.w, b.w);
    return r;
}

// ---------------- init ----------------
__global__ __launch_bounds__(256) void k_init(int* __restrict__ deg, unsigned* __restrict__ xg){
    int i = blockIdx.x * 256 + threadIdx.x;
    if (i < N_NODES) deg[i] = 0;
    if (i < N_GRAPHS * D) xg[i] = 0u;
}

// ---------------- Wt precompute: Wt[layer][n][k] = bf16(W_layer[k][n]) ----------------
__global__ __launch_bounds__(256) void k_wt(const float* __restrict__ w0, const float* __restrict__ w1,
                                            const float* __restrict__ w2, const float* __restrict__ w3,
                                            unsigned short* __restrict__ Wt){
    int id = blockIdx.x * 256 + threadIdx.x;       // 4 * 128 * 256 = 131072
    if (id >= 4 * D * 2 * D) return;
    int layer = id >> 15;          // /32768
    int rem = id & 32767;
    int n = rem >> 8;              // 0..127
    int k = rem & 255;             // 0..255
    const float* w = (layer == 0) ? w0 : (layer == 1) ? w1 : (layer == 2) ? w2 : w3;
    Wt[id] = f2bf(w[(size_t)k * D + n]);
}

// ---------------- CSR build ----------------
__global__ __launch_bounds__(256) void k_hist(const int* __restrict__ dst, int* __restrict__ deg){
    int e = blockIdx.x * 256 + threadIdx.x;
    if (e < N_EDGES) atomicAdd(&deg[dst[e]], 1);
}

__global__ __launch_bounds__(256) void k_scan1(const int* __restrict__ deg, int* __restrict__ bsum){
    __shared__ int sh[256];
    int i = blockIdx.x * 256 + threadIdx.x;
    sh[threadIdx.x] = (i < N_NODES) ? deg[i] : 0;
    __syncthreads();
    for (int s = 128; s > 0; s >>= 1){
        if (threadIdx.x < s) sh[threadIdx.x] += sh[threadIdx.x + s];
        __syncthreads();
    }
    if (threadIdx.x == 0) bsum[blockIdx.x] = sh[0];
}

__global__ __launch_bounds__(256) void k_scan2(const int* __restrict__ bsum, int* __restrict__ bbase){
    __shared__ int sh[256];
    int t = threadIdx.x;
    int v = (t < SCAN_BLOCKS) ? bsum[t] : 0;
    sh[t] = v;
    __syncthreads();
    for (int d = 1; d < 256; d <<= 1){
        int tv = (t >= d) ? sh[t - d] : 0;
        __syncthreads();
        sh[t] += tv;
        __syncthreads();
    }
    if (t < SCAN_BLOCKS) bbase[t] = sh[t] - v;   // exclusive
}

__global__ __launch_bounds__(256) void k_scan3(const int* __restrict__ deg, const int* __restrict__ bbase,
                                               int* __restrict__ off, int* __restrict__ cursor){
    __shared__ int sh[256];
    int t = threadIdx.x;
    int i = blockIdx.x * 256 + t;
    int v = (i < N_NODES) ? deg[i] : 0;
    sh[t] = v;
    __syncthreads();
    for (int d = 1; d < 256; d <<= 1){
        int tv = (t >= d) ? sh[t - d] : 0;
        __syncthreads();
        sh[t] += tv;
        __syncthreads();
    }
    if (i < N_NODES){
        int e = bbase[blockIdx.x] + sh[t] - v;
        off[i] = e;
        cursor[i] = e;
    }
}

__global__ __launch_bounds__(256) void k_fill(const int* __restrict__ src, const int* __restrict__ dst,
                                              int* __restrict__ cursor, int* __restrict__ csr){
    int e = blockIdx.x * 256 + threadIdx.x;
    if (e < N_EDGES){
        int d = dst[e];
        int p = atomicAdd(&cursor[d], 1);
        csr[p] = src[e];
    }
}

// ---------------- per-step: segment-max aggregate (gather, bf16 out) ----------------
__global__ __launch_bounds__(256) void k_agg(const float* __restrict__ h, const int* __restrict__ off,
                                             const int* __restrict__ deg, const int* __restrict__ csr,
                                             unsigned short* __restrict__ aggb){
    int node = blockIdx.x * 4 + (threadIdx.x >> 6);
    int lane = threadIdx.x & 63;
    if (node >= N_NODES) return;
    int q  = lane & 31;
    int hf = lane >> 5;
    int n = deg[node];
    int base = off[node];
    const float NEG = -INFINITY;
    float4 a0 = make_float4(NEG, NEG, NEG, NEG);
    float4 a1 = a0, a2 = a0, a3 = a0;
    int i = 0;
    for (; i + 8 <= n; i += 8){
        int b4 = base + i + 4 * hf;
        int s0 = csr[b4 + 0];
        int s1 = csr[b4 + 1];
        int s2 = csr[b4 + 2];
        int s3 = csr[b4 + 3];
        float4 v0 = *(const float4*)&h[(size_t)s0 * D + 4 * q];
        float4 v1 = *(const float4*)&h[(size_t)s1 * D + 4 * q];
        float4 v2 = *(const float4*)&h[(size_t)s2 * D + 4 * q];
        float4 v3 = *(const float4*)&h[(size_t)s3 * D + 4 * q];
        a0 = max4(a0, v0); a1 = max4(a1, v1);
        a2 = max4(a2, v2); a3 = max4(a3, v3);
    }
    for (; i + 2 <= n; i += 2){
        int s0 = csr[base + i + hf];
        float4 v0 = *(const float4*)&h[(size_t)s0 * D + 4 * q];
        a0 = max4(a0, v0);
    }
    if (i < n && hf == 0){
        int s0 = csr[base + i];
        float4 v0 = *(const float4*)&h[(size_t)s0 * D + 4 * q];
        a1 = max4(a1, v0);
    }
    a0 = max4(max4(a0, a1), max4(a2, a3));
    float4 o;
    o.x = fmaxf(a0.x, __shfl_xor(a0.x, 32, 64));
    o.y = fmaxf(a0.y, __shfl_xor(a0.y, 32, 64));
    o.z = fmaxf(a0.z, __shfl_xor(a0.z, 32, 64));
    o.w = fmaxf(a0.w, __shfl_xor(a0.w, 32, 64));
    if (n == 0){ o = make_float4(0.f, 0.f, 0.f, 0.f); }
    if (hf == 0){
        ushort4 r;
        r.x = f2bf(o.x); r.y = f2bf(o.y); r.z = f2bf(o.z); r.w = f2bf(o.w);
        *(ushort4*)&aggb[(size_t)node * D + 4 * q] = r;
    }
}

// ---------------- per-step: MFMA GEMM  hout = leaky([h|agg]_bf16 @ Wt^T + b) (+h) ----------------
// block = 64 nodes x 128 outputs, 4 waves; wave w owns nodes w*16..w*16+15 (M=16), all 128 outputs.
__global__ __launch_bounds__(256) void k_gemm(const float* __restrict__ hin, const unsigned short* __restrict__ aggb,
                                              const unsigned short* __restrict__ Wt, const float* __restrict__ b,
                                              float* __restrict__ hout, int add_skip){
    __shared__ unsigned short zt[64 * ZP];
    int tid = threadIdx.x;
    int nb = blockIdx.x * 64;

    // stage h half: 64 rows x 32 float4
    #pragma unroll
    for (int j = 0; j < 8; j++){
        int idx = j * 256 + tid;          // 0..2047
        int row = idx >> 5;
        int q = idx & 31;
        int node = nb + row;
        float4 v = make_float4(0.f, 0.f, 0.f, 0.f);
        if (node < N_NODES) v = *(const float4*)&hin[(size_t)node * D + 4 * q];
        ushort4 r;
        r.x = f2bf(v.x); r.y = f2bf(v.y); r.z = f2bf(v.z); r.w = f2bf(v.w);
        *(ushort4*)&zt[row * ZP + 4 * q] = r;
    }
    // stage agg half: 64 rows x 32 ushort4
    #pragma unroll
    for (int j = 0; j < 8; j++){
        int idx = j * 256 + tid;
        int row = idx >> 5;
        int q = idx & 31;
        int node = nb + row;
        ushort4 r = make_ushort4(0, 0, 0, 0);
        if (node < N_NODES) r = *(const ushort4*)&aggb[(size_t)node * D + 4 * q];
        *(ushort4*)&zt[row * ZP + D + 4 * q] = r;
    }
    __syncthreads();

    int wv = tid >> 6;
    int lane = tid & 63;
    int col = lane & 15;
    int quad = lane >> 4;
    int m0 = wv * 16;

    f32x4 acc[8];
    #pragma unroll
    for (int nt = 0; nt < 8; nt++) acc[nt] = (f32x4){0.f, 0.f, 0.f, 0.f};

    const unsigned short* zrow = &zt[(m0 + col) * ZP + quad * 8];
    const unsigned short* wrow = &Wt[(size_t)col * 256 + quad * 8];   // + nt*16*256 + ks*32

    #pragma unroll
    for (int ks = 0; ks < 8; ks++){
        bf16x8 afrag = *(const bf16x8*)&zrow[ks * 32];
        #pragma unroll
        for (int nt = 0; nt < 8; nt++){
            bf16x8 bfrag = *(const bf16x8*)&wrow[nt * 16 * 256 + ks * 32];
            acc[nt] = __builtin_amdgcn_mfma_f32_16x16x32_bf16(afrag, bfrag, acc[nt], 0, 0, 0);
        }
    }

    // epilogue: C/D mapping col=lane&15, row=quad*4+reg
    #pragma unroll
    for (int nt = 0; nt < 8; nt++){
        int feat = nt * 16 + col;
        float bb_ = b[feat];
        #pragma unroll
        for (int r = 0; r < 4; r++){
            int node = nb + m0 + quad * 4 + r;
            if (node < N_NODES){
                float y = leaky(acc[nt][r] + bb_);
                if (add_skip) y += hin[(size_t)node * D + feat];
                hout[(size_t)node * D + feat] = y;
            }
        }
    }
}

// ---------------- global max-pool per graph (batch sorted, int32) ----------------
__global__ __launch_bounds__(256) void k_pool(const float* __restrict__ h, const int* __restrict__ batch,
                                              unsigned* __restrict__ xg){
    __shared__ unsigned lmax[2 * D];
    int tid = threadIdx.x;
    lmax[tid] = 0u;
    __syncthreads();

    int n0 = blockIdx.x * PBLK;
    int g0 = batch[n0];
    int q = tid & 31;
    int s = tid >> 5;
    int i0 = n0 + s * PSL;
    int i1 = min(i0 + PSL, N_NODES);

    if (i0 < N_NODES){
        const float NEG = -INFINITY;
        float4 m = make_float4(NEG, NEG, NEG, NEG);
        int curg = batch[i0];
        int i = i0;
        for (; i + 2 <= i1; i += 2){
            int ga = batch[i];
            int gb = batch[i + 1];
            float4 va = *(const float4*)&h[(size_t)i * D + 4 * q];
            float4 vb = *(const float4*)&h[(size_t)(i + 1) * D + 4 * q];
            if (ga != curg){
                int rel = curg - g0;
                unsigned* dst = (rel < 2) ? &lmax[rel * D + 4 * q] : &xg[curg * D + 4 * q];
                atomicMax(dst + 0, fenc(m.x)); atomicMax(dst + 1, fenc(m.y));
                atomicMax(dst + 2, fenc(m.z)); atomicMax(dst + 3, fenc(m.w));
                curg = ga; m = make_float4(NEG, NEG, NEG, NEG);
            }
            m = max4(m, va);
            if (gb != curg){
                int rel = curg - g0;
                unsigned* dst = (rel < 2) ? &lmax[rel * D + 4 * q] : &xg[curg * D + 4 * q];
                atomicMax(dst + 0, fenc(m.x)); atomicMax(dst + 1, fenc(m.y));
                atomicMax(dst + 2, fenc(m.z)); atomicMax(dst + 3, fenc(m.w));
                curg = gb; m = make_float4(NEG, NEG, NEG, NEG);
            }
            m = max4(m, vb);
        }
        if (i < i1){
            int ga = batch[i];
            float4 va = *(const float4*)&h[(size_t)i * D + 4 * q];
            if (ga != curg){
                int rel = curg - g0;
                unsigned* dst = (rel < 2) ? &lmax[rel * D + 4 * q] : &xg[curg * D + 4 * q];
                atomicMax(dst + 0, fenc(m.x)); atomicMax(dst + 1, fenc(m.y));
                atomicMax(dst + 2, fenc(m.z)); atomicMax(dst + 3, fenc(m.w));
                curg = ga; m = make_float4(NEG, NEG, NEG, NEG);
            }
            m = max4(m, va);
        }
        {
            int rel = curg - g0;
            unsigned* dst = (rel < 2) ? &lmax[rel * D + 4 * q] : &xg[curg * D + 4 * q];
            atomicMax(dst + 0, fenc(m.x)); atomicMax(dst + 1, fenc(m.y));
            atomicMax(dst + 2, fenc(m.z)); atomicMax(dst + 3, fenc(m.w));
        }
    }
    __syncthreads();

    if (tid < D){
        unsigned e = lmax[tid];
        if (e) atomicMax(&xg[g0 * D + tid], e);
    } else {
        int f = tid - D;
        int g1 = g0 + 1;
        if (g1 < N_GRAPHS){
            unsigned e = lmax[D + f];
            if (e) atomicMax(&xg[g1 * D + f], e);
        }
    }
}

// ---------------- head: leaky(xg @ wg[:128] + bg) ----------------
__global__ __launch_bounds__(256) void k_final(const unsigned* __restrict__ xg_enc, const float* __restrict__ wg,
                                               const float* __restrict__ bg, float* __restrict__ out){
    __shared__ float xs[N_GRAPHS * D];
    int tid = threadIdx.x;
    for (int i = tid; i < N_GRAPHS * D; i += 256){
        unsigned e = xg_enc[i];
        xs[i] = (e == 0u) ? 0.f : fdec(e);
    }
    __syncthreads();
    int g = tid >> 4;
    int j0 = (tid & 15) * 8;
    float acc[8];
    #pragma unroll
    for (int j = 0; j < 8; j++) acc[j] = 0.f;
    for (int k = 0; k < D; k++){
        float xv = xs[g * D + k];
        const float* wr = &wg[(size_t)k * D + j0];
        #pragma unroll
        for (int j = 0; j < 8; j++) acc[j] = fmaf(xv, wr[j], acc[j]);
    }
    float* orow = &out[(size_t)N_NODES * D + g * D + j0];
    #pragma unroll
    for (int j = 0; j < 8; j++) orow[j] = leaky(acc[j] + bg[j0 + j]);
}

extern "C" void kernel_launch(void* const* d_in, const int* in_sizes, int n_in,
                              void* d_out, int out_size, void* d_ws, size_t ws_size,
                              hipStream_t stream){
    const float* x = (const float*)d_in[0];
    const int* eidx  = (const int*)d_in[1];   // harness converts integer inputs to int32
    const int* batch = (const int*)d_in[2];
    const float* w[4]  = {(const float*)d_in[4], (const float*)d_in[6], (const float*)d_in[8], (const float*)d_in[10]};
    const float* bb[4] = {(const float*)d_in[5], (const float*)d_in[7], (const float*)d_in[9], (const float*)d_in[11]};
    const float* wg = (const float*)d_in[12];
    const float* bg = (const float*)d_in[13];
    const int* esrc = eidx;
    const int* edst = eidx + N_EDGES;

    // workspace layout (total ~16.9 MB)
    char* ws = (char*)d_ws;
    int* deg    = (int*)ws;       ws += 50048 * 4;
    int* off    = (int*)ws;       ws += 50048 * 4;
    int* cursor = (int*)ws;       ws += 50048 * 4;
    int* bsum   = (int*)ws;       ws += 256 * 4;
    int* bbase  = (int*)ws;       ws += 256 * 4;
    int* csr    = (int*)ws;       ws += N_EDGES * 4;
    unsigned* xg_enc = (unsigned*)ws; ws += N_GRAPHS * D * 4;
    unsigned short* Wt = (unsigned short*)ws; ws += 4 * 2 * D * D * 2;  // 4 layers, [n][k] bf16
    unsigned short* aggb = (unsigned short*)(((uintptr_t)ws + 255) & ~(uintptr_t)255); // 12.8 MB
    float* h    = (float*)d_out;

    hipMemcpyAsync(h, x, (size_t)N_NODES * D * 4, hipMemcpyDeviceToDevice, stream);

    k_init <<<SCAN_BLOCKS, 256, 0, stream>>>(deg, xg_enc);
    k_wt   <<<512, 256, 0, stream>>>(w[0], w[1], w[2], w[3], Wt);
    k_hist <<<(N_EDGES + 255) / 256, 256, 0, stream>>>(edst, deg);
    k_scan1<<<SCAN_BLOCKS, 256, 0, stream>>>(deg, bsum);
    k_scan2<<<1, 256, 0, stream>>>(bsum, bbase);
    k_scan3<<<SCAN_BLOCKS, 256, 0, stream>>>(deg, bbase, off, cursor);
    k_fill <<<(N_EDGES + 255) / 256, 256, 0, stream>>>(esrc, edst, cursor, csr);

    for (int s = 0; s < 4; s++){
        k_agg <<<(N_NODES + 3) / 4, 256, 0, stream>>>(h, off, deg, csr, aggb);
        k_gemm<<<(N_NODES + 63) / 64, 256, 0, stream>>>(h, aggb, Wt + (size_t)s * 2 * D * D, bb[s], h, s > 0);
    }

    k_pool <<<(N_NODES + PBLK - 1) / PBLK, 256, 0, stream>>>(h, batch, xg_enc);
    k_final<<<1, 256, 0, stream>>>(xg_enc, wg, bg, (float*)d_out);
}

// Round 6
// 517.971 us; speedup vs baseline: 1.6556x; 1.1989x over previous
//
#include <hip/hip_runtime.h>
#include <stdint.h>
#include <math.h>

#define N_NODES 50000
#define N_EDGES 800000
#define D 128
#define N_GRAPHS 16
#define ZP 264         // LDS z-tile row pitch in bf16 elems (264*2B=528B -> 16B-aligned rows)
#define PBLK 128       // nodes per pool block
#define PSL 16         // nodes per pool slice
#define SCAN_BLOCKS 196
#define CSR_CAP 960000 // sum of 4-padded degrees <= 800000 + 3*50000 = 950000

typedef __attribute__((ext_vector_type(8))) short bf16x8;   // 8 bf16 (4 VGPRs)
typedef __attribute__((ext_vector_type(4))) float f32x4;

__device__ __forceinline__ float leaky(float y){ return y > 0.f ? y : 0.01f * y; }

// monotonic float->uint encoding for atomic max; 0 = "empty" marker
__device__ __forceinline__ unsigned fenc(float f){
    unsigned u = __float_as_uint(f);
    return (f >= 0.f) ? (u | 0x80000000u) : ~u;
}
__device__ __forceinline__ float fdec(unsigned e){
    return (e & 0x80000000u) ? __uint_as_float(e & 0x7fffffffu) : __uint_as_float(~e);
}

// bf16 pack/unpack (round-to-nearest-even)
__device__ __forceinline__ unsigned short f2bf(float f){
    unsigned u = __float_as_uint(f);
    u += 0x7fffu + ((u >> 16) & 1u);
    return (unsigned short)(u >> 16);
}
__device__ __forceinline__ unsigned pk2(float lo, float hi){
    return (unsigned)f2bf(lo) | ((unsigned)f2bf(hi) << 16);
}
__device__ __forceinline__ void maxbf8(float a[8], uint4 v){
    a[0] = fmaxf(a[0], __uint_as_float(v.x << 16)); a[1] = fmaxf(a[1], __uint_as_float(v.x & 0xffff0000u));
    a[2] = fmaxf(a[2], __uint_as_float(v.y << 16)); a[3] = fmaxf(a[3], __uint_as_float(v.y & 0xffff0000u));
    a[4] = fmaxf(a[4], __uint_as_float(v.z << 16)); a[5] = fmaxf(a[5], __uint_as_float(v.z & 0xffff0000u));
    a[6] = fmaxf(a[6], __uint_as_float(v.w << 16)); a[7] = fmaxf(a[7], __uint_as_float(v.w & 0xffff0000u));
}
__device__ __forceinline__ float4 max4(float4 a, float4 b){
    float4 r;
    r.x = fmaxf(a.x, b.x); r.y = fmaxf(a.y, b.y);
    r.z = fmaxf(a.z, b.z); r.w = fmaxf(a.w, b.w);
    return r;
}

// ---------------- init ----------------
__global__ __launch_bounds__(256) void k_init(int* __restrict__ deg, unsigned* __restrict__ xg){
    int i = blockIdx.x * 256 + threadIdx.x;
    if (i < N_NODES) deg[i] = 0;
    if (i < N_GRAPHS * D) xg[i] = 0u;
}

// ---------------- f32 -> bf16 shadow convert (4 floats/thread) ----------------
__global__ __launch_bounds__(256) void k_cvt(const float* __restrict__ src, unsigned short* __restrict__ dst){
    int id = blockIdx.x * 256 + threadIdx.x;       // 1.6M threads
    if (id < N_NODES * D / 4){
        float4 v = ((const float4*)src)[id];
        uint2 r; r.x = pk2(v.x, v.y); r.y = pk2(v.z, v.w);
        ((uint2*)dst)[id] = r;
    }
}

// ---------------- Wt precompute: Wt[layer][n][k] = bf16(W_layer[k][n]) ----------------
__global__ __launch_bounds__(256) void k_wt(const float* __restrict__ w0, const float* __restrict__ w1,
                                            const float* __restrict__ w2, const float* __restrict__ w3,
                                            unsigned short* __restrict__ Wt){
    int id = blockIdx.x * 256 + threadIdx.x;       // 131072
    if (id >= 4 * D * 2 * D) return;
    int layer = id >> 15;
    int rem = id & 32767;
    int n = rem >> 8;
    int k = rem & 255;
    const float* w = (layer == 0) ? w0 : (layer == 1) ? w1 : (layer == 2) ? w2 : w3;
    Wt[id] = f2bf(w[(size_t)k * D + n]);
}

// ---------------- CSR build (int4 reads, ushort entries, 4-aligned segments) ----------------
__global__ __launch_bounds__(256) void k_hist(const int* __restrict__ dst, int* __restrict__ deg){
    int e4 = blockIdx.x * 256 + threadIdx.x;
    if (e4 < N_EDGES / 4){
        int4 d = ((const int4*)dst)[e4];
        atomicAdd(&deg[d.x], 1); atomicAdd(&deg[d.y], 1);
        atomicAdd(&deg[d.z], 1); atomicAdd(&deg[d.w], 1);
    }
}

__global__ __launch_bounds__(256) void k_scan1(const int* __restrict__ deg, int* __restrict__ bsum){
    __shared__ int sh[256];
    int i = blockIdx.x * 256 + threadIdx.x;
    int dv = (i < N_NODES) ? deg[i] : 0;
    sh[threadIdx.x] = (dv + 3) & ~3;               // 4-padded
    __syncthreads();
    for (int s = 128; s > 0; s >>= 1){
        if (threadIdx.x < s) sh[threadIdx.x] += sh[threadIdx.x + s];
        __syncthreads();
    }
    if (threadIdx.x == 0) bsum[blockIdx.x] = sh[0];
}

__global__ __launch_bounds__(256) void k_scan2(const int* __restrict__ bsum, int* __restrict__ bbase){
    __shared__ int sh[256];
    int t = threadIdx.x;
    int v = (t < SCAN_BLOCKS) ? bsum[t] : 0;
    sh[t] = v;
    __syncthreads();
    for (int d = 1; d < 256; d <<= 1){
        int tv = (t >= d) ? sh[t - d] : 0;
        __syncthreads();
        sh[t] += tv;
        __syncthreads();
    }
    if (t < SCAN_BLOCKS) bbase[t] = sh[t] - v;   // exclusive
}

__global__ __launch_bounds__(256) void k_scan3(const int* __restrict__ deg, const int* __restrict__ bbase,
                                               int* __restrict__ off, int* __restrict__ cursor){
    __shared__ int sh[256];
    int t = threadIdx.x;
    int i = blockIdx.x * 256 + t;
    int dv = (i < N_NODES) ? deg[i] : 0;
    int v = (dv + 3) & ~3;                        // 4-padded
    sh[t] = v;
    __syncthreads();
    for (int d = 1; d < 256; d <<= 1){
        int tv = (t >= d) ? sh[t - d] : 0;
        __syncthreads();
        sh[t] += tv;
        __syncthreads();
    }
    if (i < N_NODES){
        int e = bbase[blockIdx.x] + sh[t] - v;    // 4-aligned base
        off[i] = e;
        cursor[i] = e;
    }
}

__global__ __launch_bounds__(256) void k_fill(const int* __restrict__ src, const int* __restrict__ dst,
                                              int* __restrict__ cursor, unsigned short* __restrict__ csr16){
    int e4 = blockIdx.x * 256 + threadIdx.x;
    if (e4 < N_EDGES / 4){
        int4 d = ((const int4*)dst)[e4];
        int4 s = ((const int4*)src)[e4];
        int p;
        p = atomicAdd(&cursor[d.x], 1); csr16[p] = (unsigned short)s.x;
        p = atomicAdd(&cursor[d.y], 1); csr16[p] = (unsigned short)s.y;
        p = atomicAdd(&cursor[d.z], 1); csr16[p] = (unsigned short)s.z;
        p = atomicAdd(&cursor[d.w], 1); csr16[p] = (unsigned short)s.w;
    }
}

// ---------------- fused step: agg-gather (bf16) + MFMA GEMM + leaky + skip ----------------
// block = 64 nodes, 256 threads (4 waves). Wave w owns nodes w*16..w*16+15.
// Phase A: 16-lane groups gather-max rows of hb per node into LDS agg half.
// Phase B: stage bf16 h-half from hb. Then 16x16x32 bf16 MFMA vs Wt, f32 epilogue.
__global__ __launch_bounds__(256) void k_step(const float* __restrict__ hin,
                                              const unsigned short* __restrict__ hb,
                                              const unsigned short* __restrict__ csr16,
                                              const int* __restrict__ deg, const int* __restrict__ off,
                                              const unsigned short* __restrict__ Wt, const float* __restrict__ b,
                                              float* __restrict__ hout, int add_skip){
    __shared__ unsigned short zt[64 * ZP];
    int tid = threadIdx.x;
    int nb = blockIdx.x * 64;
    int lane = tid & 63;
    int wv = tid >> 6;

    // Phase B: stage h-half (coalesced 16B chunks)
    #pragma unroll
    for (int j = 0; j < 4; j++){
        int idx = j * 256 + tid;          // 0..1023
        int row = idx >> 4;               // 0..63
        int ch  = idx & 15;               // 16B chunk -> feats ch*8..+7
        int node = nb + row;
        uint4 v = make_uint4(0u, 0u, 0u, 0u);
        if (node < N_NODES) v = *(const uint4*)&hb[(size_t)node * D + ch * 8];
        *(uint4*)&zt[row * ZP + ch * 8] = v;
    }

    // Phase A: gather-max. 16-lane group per node, 4 nodes per wave concurrently.
    {
        int chunk = lane & 15;            // feats chunk*8..+7
        int sub   = lane >> 4;            // node-sub within wave
        #pragma unroll
        for (int g = 0; g < 4; g++){
            int ml = wv * 16 + g * 4 + sub;   // local node 0..63
            int node = nb + ml;
            int n = 0, base = 0;
            if (node < N_NODES){ n = deg[node]; base = off[node]; }
            const float NEG = -INFINITY;
            float a[8] = {NEG, NEG, NEG, NEG, NEG, NEG, NEG, NEG};
            int i = 0;
            for (; i + 4 <= n; i += 4){
                ushort4 ss = *(const ushort4*)&csr16[base + i];   // base 4-aligned -> 8B aligned
                uint4 v0 = *(const uint4*)&hb[(size_t)ss.x * D + chunk * 8];
                uint4 v1 = *(const uint4*)&hb[(size_t)ss.y * D + chunk * 8];
                uint4 v2 = *(const uint4*)&hb[(size_t)ss.z * D + chunk * 8];
                uint4 v3 = *(const uint4*)&hb[(size_t)ss.w * D + chunk * 8];
                maxbf8(a, v0); maxbf8(a, v1); maxbf8(a, v2); maxbf8(a, v3);
            }
            for (; i < n; i++){
                int s = csr16[base + i];
                uint4 v = *(const uint4*)&hb[(size_t)s * D + chunk * 8];
                maxbf8(a, v);
            }
            uint4 r;
            if (n == 0){
                r = make_uint4(0u, 0u, 0u, 0u);
            } else {
                r.x = pk2(a[0], a[1]); r.y = pk2(a[2], a[3]);
                r.z = pk2(a[4], a[5]); r.w = pk2(a[6], a[7]);
            }
            *(uint4*)&zt[ml * ZP + D + chunk * 8] = r;
        }
    }
    __syncthreads();

    // MFMA: 16 nodes x 128 outputs per wave
    int col = lane & 15;
    int quad = lane >> 4;
    int m0 = wv * 16;

    f32x4 acc[8];
    #pragma unroll
    for (int nt = 0; nt < 8; nt++) acc[nt] = (f32x4){0.f, 0.f, 0.f, 0.f};

    const unsigned short* zrow = &zt[(m0 + col) * ZP + quad * 8];
    const unsigned short* wrow = &Wt[(size_t)col * 256 + quad * 8];

    #pragma unroll
    for (int ks = 0; ks < 8; ks++){
        bf16x8 afrag = *(const bf16x8*)&zrow[ks * 32];
        #pragma unroll
        for (int nt = 0; nt < 8; nt++){
            bf16x8 bfrag = *(const bf16x8*)&wrow[nt * 16 * 256 + ks * 32];
            acc[nt] = __builtin_amdgcn_mfma_f32_16x16x32_bf16(afrag, bfrag, acc[nt], 0, 0, 0);
        }
    }

    // epilogue: C/D mapping col=lane&15, row=quad*4+reg
    #pragma unroll
    for (int nt = 0; nt < 8; nt++){
        int feat = nt * 16 + col;
        float bb_ = b[feat];
        #pragma unroll
        for (int r = 0; r < 4; r++){
            int node = nb + m0 + quad * 4 + r;
            if (node < N_NODES){
                float y = leaky(acc[nt][r] + bb_);
                if (add_skip) y += hin[(size_t)node * D + feat];
                hout[(size_t)node * D + feat] = y;
            }
        }
    }
}

// ---------------- global max-pool per graph (batch sorted, int32) ----------------
__global__ __launch_bounds__(256) void k_pool(const float* __restrict__ h, const int* __restrict__ batch,
                                              unsigned* __restrict__ xg){
    __shared__ unsigned lmax[2 * D];
    int tid = threadIdx.x;
    lmax[tid] = 0u;
    __syncthreads();

    int n0 = blockIdx.x * PBLK;
    int g0 = batch[n0];
    int q = tid & 31;
    int s = tid >> 5;
    int i0 = n0 + s * PSL;
    int i1 = min(i0 + PSL, N_NODES);

    if (i0 < N_NODES){
        const float NEG = -INFINITY;
        float4 m = make_float4(NEG, NEG, NEG, NEG);
        int curg = batch[i0];
        int i = i0;
        for (; i + 2 <= i1; i += 2){
            int ga = batch[i];
            int gb = batch[i + 1];
            float4 va = *(const float4*)&h[(size_t)i * D + 4 * q];
            float4 vb = *(const float4*)&h[(size_t)(i + 1) * D + 4 * q];
            if (ga != curg){
                int rel = curg - g0;
                unsigned* dst = (rel < 2) ? &lmax[rel * D + 4 * q] : &xg[curg * D + 4 * q];
                atomicMax(dst + 0, fenc(m.x)); atomicMax(dst + 1, fenc(m.y));
                atomicMax(dst + 2, fenc(m.z)); atomicMax(dst + 3, fenc(m.w));
                curg = ga; m = make_float4(NEG, NEG, NEG, NEG);
            }
            m = max4(m, va);
            if (gb != curg){
                int rel = curg - g0;
                unsigned* dst = (rel < 2) ? &lmax[rel * D + 4 * q] : &xg[curg * D + 4 * q];
                atomicMax(dst + 0, fenc(m.x)); atomicMax(dst + 1, fenc(m.y));
                atomicMax(dst + 2, fenc(m.z)); atomicMax(dst + 3, fenc(m.w));
                curg = gb; m = make_float4(NEG, NEG, NEG, NEG);
            }
            m = max4(m, vb);
        }
        if (i < i1){
            int ga = batch[i];
            float4 va = *(const float4*)&h[(size_t)i * D + 4 * q];
            if (ga != curg){
                int rel = curg - g0;
                unsigned* dst = (rel < 2) ? &lmax[rel * D + 4 * q] : &xg[curg * D + 4 * q];
                atomicMax(dst + 0, fenc(m.x)); atomicMax(dst + 1, fenc(m.y));
                atomicMax(dst + 2, fenc(m.z)); atomicMax(dst + 3, fenc(m.w));
                curg = ga; m = make_float4(NEG, NEG, NEG, NEG);
            }
            m = max4(m, va);
        }
        {
            int rel = curg - g0;
            unsigned* dst = (rel < 2) ? &lmax[rel * D + 4 * q] : &xg[curg * D + 4 * q];
            atomicMax(dst + 0, fenc(m.x)); atomicMax(dst + 1, fenc(m.y));
            atomicMax(dst + 2, fenc(m.z)); atomicMax(dst + 3, fenc(m.w));
        }
    }
    __syncthreads();

    if (tid < D){
        unsigned e = lmax[tid];
        if (e) atomicMax(&xg[g0 * D + tid], e);
    } else {
        int f = tid - D;
        int g1 = g0 + 1;
        if (g1 < N_GRAPHS){
            unsigned e = lmax[D + f];
            if (e) atomicMax(&xg[g1 * D + f], e);
        }
    }
}

// ---------------- head: leaky(xg @ wg[:128] + bg) ----------------
__global__ __launch_bounds__(256) void k_final(const unsigned* __restrict__ xg_enc, const float* __restrict__ wg,
                                               const float* __restrict__ bg, float* __restrict__ out){
    __shared__ float xs[N_GRAPHS * D];
    int tid = threadIdx.x;
    for (int i = tid; i < N_GRAPHS * D; i += 256){
        unsigned e = xg_enc[i];
        xs[i] = (e == 0u) ? 0.f : fdec(e);
    }
    __syncthreads();
    int g = tid >> 4;
    int j0 = (tid & 15) * 8;
    float acc[8];
    #pragma unroll
    for (int j = 0; j < 8; j++) acc[j] = 0.f;
    for (int k = 0; k < D; k++){
        float xv = xs[g * D + k];
        const float* wr = &wg[(size_t)k * D + j0];
        #pragma unroll
        for (int j = 0; j < 8; j++) acc[j] = fmaf(xv, wr[j], acc[j]);
    }
    float* orow = &out[(size_t)N_NODES * D + g * D + j0];
    #pragma unroll
    for (int j = 0; j < 8; j++) orow[j] = leaky(acc[j] + bg[j0 + j]);
}

extern "C" void kernel_launch(void* const* d_in, const int* in_sizes, int n_in,
                              void* d_out, int out_size, void* d_ws, size_t ws_size,
                              hipStream_t stream){
    const float* x = (const float*)d_in[0];
    const int* eidx  = (const int*)d_in[1];   // harness converts integer inputs to int32
    const int* batch = (const int*)d_in[2];
    const float* w[4]  = {(const float*)d_in[4], (const float*)d_in[6], (const float*)d_in[8], (const float*)d_in[10]};
    const float* bb[4] = {(const float*)d_in[5], (const float*)d_in[7], (const float*)d_in[9], (const float*)d_in[11]};
    const float* wg = (const float*)d_in[12];
    const float* bg = (const float*)d_in[13];
    const int* esrc = eidx;
    const int* edst = eidx + N_EDGES;

    // workspace layout (~15.6 MB)
    char* ws = (char*)d_ws;
    int* deg    = (int*)ws;       ws += 50048 * 4;
    int* off    = (int*)ws;       ws += 50048 * 4;
    int* cursor = (int*)ws;       ws += 50048 * 4;
    int* bsum   = (int*)ws;       ws += 256 * 4;
    int* bbase  = (int*)ws;       ws += 256 * 4;
    unsigned* xg_enc = (unsigned*)ws; ws += N_GRAPHS * D * 4;
    unsigned short* Wt = (unsigned short*)ws; ws += 4 * 2 * D * D * 2;  // 4 layers, [n][k] bf16
    unsigned short* csr16 = (unsigned short*)ws; ws += CSR_CAP * 2;
    unsigned short* hb = (unsigned short*)(((uintptr_t)ws + 255) & ~(uintptr_t)255); // 12.8 MB bf16 shadow of h
    float* h    = (float*)d_out;   // f32 h lives in the output buffer (fully written by step 0)

    k_init <<<SCAN_BLOCKS, 256, 0, stream>>>(deg, xg_enc);
    k_wt   <<<512, 256, 0, stream>>>(w[0], w[1], w[2], w[3], Wt);
    k_cvt  <<<6250, 256, 0, stream>>>(x, hb);                          // hb = bf16(x)
    k_hist <<<(N_EDGES / 4 + 255) / 256, 256, 0, stream>>>(edst, deg);
    k_scan1<<<SCAN_BLOCKS, 256, 0, stream>>>(deg, bsum);
    k_scan2<<<1, 256, 0, stream>>>(bsum, bbase);
    k_scan3<<<SCAN_BLOCKS, 256, 0, stream>>>(deg, bbase, off, cursor);
    k_fill <<<(N_EDGES / 4 + 255) / 256, 256, 0, stream>>>(esrc, edst, cursor, csr16);

    for (int s = 0; s < 4; s++){
        k_step<<<(N_NODES + 63) / 64, 256, 0, stream>>>(h, hb, csr16, deg, off,
                                                        Wt + (size_t)s * 2 * D * D, bb[s], h, s > 0);
        if (s < 3) k_cvt<<<6250, 256, 0, stream>>>(h, hb);             // refresh bf16 shadow
    }

    k_pool <<<(N_NODES + PBLK - 1) / PBLK, 256, 0, stream>>>(h, batch, xg_enc);
    k_final<<<1, 256, 0, stream>>>(xg_enc, wg, bg, (float*)d_out);
}

// Round 7
// 475.137 us; speedup vs baseline: 1.8048x; 1.0902x over previous
//
#include <hip/hip_runtime.h>
#include <stdint.h>
#include <math.h>

#define N_NODES 50000
#define N_EDGES 800000
#define D 128
#define N_GRAPHS 16
#define ZP 264         // LDS z-tile row pitch in bf16 elems (264*2B=528B -> 16B-aligned rows)
#define PBLK 128       // nodes per pool block
#define PSL 16         // nodes per pool slice
#define SCAN_BLOCKS 196
#define CSR_CAP 1150400 // sum of 8-padded degrees <= 800000 + 7*50000

typedef __attribute__((ext_vector_type(8))) short bf16x8;   // 8 bf16 (4 VGPRs)
typedef __attribute__((ext_vector_type(4))) float f32x4;

__device__ __forceinline__ float leaky(float y){ return y > 0.f ? y : 0.01f * y; }

// monotonic float->uint encoding for atomic max; 0 = "empty" marker
__device__ __forceinline__ unsigned fenc(float f){
    unsigned u = __float_as_uint(f);
    return (f >= 0.f) ? (u | 0x80000000u) : ~u;
}
__device__ __forceinline__ float fdec(unsigned e){
    return (e & 0x80000000u) ? __uint_as_float(e & 0x7fffffffu) : __uint_as_float(~e);
}

// bf16 pack/unpack (round-to-nearest-even)
__device__ __forceinline__ unsigned short f2bf(float f){
    unsigned u = __float_as_uint(f);
    u += 0x7fffu + ((u >> 16) & 1u);
    return (unsigned short)(u >> 16);
}
__device__ __forceinline__ unsigned pk2(float lo, float hi){
    return (unsigned)f2bf(lo) | ((unsigned)f2bf(hi) << 16);
}
__device__ __forceinline__ void maxbf8(float a[8], uint4 v){
    a[0] = fmaxf(a[0], __uint_as_float(v.x << 16)); a[1] = fmaxf(a[1], __uint_as_float(v.x & 0xffff0000u));
    a[2] = fmaxf(a[2], __uint_as_float(v.y << 16)); a[3] = fmaxf(a[3], __uint_as_float(v.y & 0xffff0000u));
    a[4] = fmaxf(a[4], __uint_as_float(v.z << 16)); a[5] = fmaxf(a[5], __uint_as_float(v.z & 0xffff0000u));
    a[6] = fmaxf(a[6], __uint_as_float(v.w << 16)); a[7] = fmaxf(a[7], __uint_as_float(v.w & 0xffff0000u));
}
__device__ __forceinline__ float4 max4(float4 a, float4 b){
    float4 r;
    r.x = fmaxf(a.x, b.x); r.y = fmaxf(a.y, b.y);
    r.z = fmaxf(a.z, b.z); r.w = fmaxf(a.w, b.w);
    return r;
}

// ---------------- combined pre-pass: hb=bf16(x), Wt transpose, zero deg/xg ----------------
__global__ __launch_bounds__(256) void k_pre(const float* __restrict__ x, unsigned short* __restrict__ hb,
                                             const float* __restrict__ w0, const float* __restrict__ w1,
                                             const float* __restrict__ w2, const float* __restrict__ w3,
                                             unsigned short* __restrict__ Wt,
                                             int* __restrict__ deg, unsigned* __restrict__ xg){
    int id = blockIdx.x * 256 + threadIdx.x;
    if (id < N_NODES * D / 4){
        float4 v = ((const float4*)x)[id];
        uint2 r; r.x = pk2(v.x, v.y); r.y = pk2(v.z, v.w);
        ((uint2*)hb)[id] = r;
    }
    if (id < 4 * D * 2 * D){
        int layer = id >> 15;
        int rem = id & 32767;
        int n = rem >> 8;
        int k = rem & 255;
        const float* w = (layer == 0) ? w0 : (layer == 1) ? w1 : (layer == 2) ? w2 : w3;
        Wt[id] = f2bf(w[(size_t)k * D + n]);
    }
    if (id < 50048) deg[id] = 0;
    if (id < N_GRAPHS * D) xg[id] = 0u;
}

// ---------------- CSR build (int4 reads, ushort entries, 8-aligned 8-padded segments) ----------------
__global__ __launch_bounds__(256) void k_hist(const int* __restrict__ dst, int* __restrict__ deg){
    int e4 = blockIdx.x * 256 + threadIdx.x;
    if (e4 < N_EDGES / 4){
        int4 d = ((const int4*)dst)[e4];
        atomicAdd(&deg[d.x], 1); atomicAdd(&deg[d.y], 1);
        atomicAdd(&deg[d.z], 1); atomicAdd(&deg[d.w], 1);
    }
}

__global__ __launch_bounds__(256) void k_scan1(const int* __restrict__ deg, int* __restrict__ bsum){
    __shared__ int sh[256];
    int i = blockIdx.x * 256 + threadIdx.x;
    int dv = (i < N_NODES) ? deg[i] : 0;
    sh[threadIdx.x] = (dv + 7) & ~7;               // 8-padded
    __syncthreads();
    for (int s = 128; s > 0; s >>= 1){
        if (threadIdx.x < s) sh[threadIdx.x] += sh[threadIdx.x + s];
        __syncthreads();
    }
    if (threadIdx.x == 0) bsum[blockIdx.x] = sh[0];
}

__global__ __launch_bounds__(256) void k_scan2(const int* __restrict__ bsum, int* __restrict__ bbase){
    __shared__ int sh[256];
    int t = threadIdx.x;
    int v = (t < SCAN_BLOCKS) ? bsum[t] : 0;
    sh[t] = v;
    __syncthreads();
    for (int d = 1; d < 256; d <<= 1){
        int tv = (t >= d) ? sh[t - d] : 0;
        __syncthreads();
        sh[t] += tv;
        __syncthreads();
    }
    if (t < SCAN_BLOCKS) bbase[t] = sh[t] - v;   // exclusive
}

__global__ __launch_bounds__(256) void k_scan3(const int* __restrict__ deg, const int* __restrict__ bbase,
                                               int* __restrict__ off, int* __restrict__ cursor){
    __shared__ int sh[256];
    int t = threadIdx.x;
    int i = blockIdx.x * 256 + t;
    int dv = (i < N_NODES) ? deg[i] : 0;
    int v = (dv + 7) & ~7;                        // 8-padded
    sh[t] = v;
    __syncthreads();
    for (int d = 1; d < 256; d <<= 1){
        int tv = (t >= d) ? sh[t - d] : 0;
        __syncthreads();
        sh[t] += tv;
        __syncthreads();
    }
    if (i < N_NODES){
        int e = bbase[blockIdx.x] + sh[t] - v;    // 8-aligned base
        off[i] = e;
        cursor[i] = e;
    }
}

__global__ __launch_bounds__(256) void k_fill(const int* __restrict__ src, const int* __restrict__ dst,
                                              int* __restrict__ cursor, unsigned short* __restrict__ csr16){
    int e4 = blockIdx.x * 256 + threadIdx.x;
    if (e4 < N_EDGES / 4){
        int4 d = ((const int4*)dst)[e4];
        int4 s = ((const int4*)src)[e4];
        int p;
        p = atomicAdd(&cursor[d.x], 1); csr16[p] = (unsigned short)s.x;
        p = atomicAdd(&cursor[d.y], 1); csr16[p] = (unsigned short)s.y;
        p = atomicAdd(&cursor[d.z], 1); csr16[p] = (unsigned short)s.z;
        p = atomicAdd(&cursor[d.w], 1); csr16[p] = (unsigned short)s.w;
    }
}

// pad each node's segment to a multiple of 8 by duplicating its first edge (max-invariant)
__global__ __launch_bounds__(256) void k_pad(const int* __restrict__ deg, const int* __restrict__ off,
                                             unsigned short* __restrict__ csr16){
    int i = blockIdx.x * 256 + threadIdx.x;
    if (i < N_NODES){
        int n = deg[i];
        if (n > 0){
            int base = off[i];
            unsigned short s0 = csr16[base];
            int n8 = (n + 7) & ~7;
            for (int j = n; j < n8; j++) csr16[base + j] = s0;
        }
    }
}

// ---------------- fused step: agg-gather (bf16, MLP=8) + MFMA GEMM + leaky + skip + hb update ------
// block = 64 nodes, 256 threads (4 waves). Wave w owns nodes w*16..w*16+15 for MFMA.
__global__ __launch_bounds__(256) void k_step(const float* __restrict__ hin,
                                              const unsigned short* __restrict__ hb,
                                              const unsigned short* __restrict__ csr16,
                                              const int* __restrict__ deg, const int* __restrict__ off,
                                              const unsigned short* __restrict__ Wt, const float* __restrict__ b,
                                              float* __restrict__ hout, unsigned short* __restrict__ hbout,
                                              int add_skip, int write_hb){
    __shared__ unsigned short zt[64 * ZP];
    int tid = threadIdx.x;
    int nb = blockIdx.x * 64;
    int lane = tid & 63;
    int wv = tid >> 6;

    // stage h-half (coalesced 16B chunks)
    #pragma unroll
    for (int j = 0; j < 4; j++){
        int idx = j * 256 + tid;          // 0..1023
        int row = idx >> 4;               // 0..63
        int ch  = idx & 15;               // 16B chunk -> feats ch*8..+7
        int node = nb + row;
        uint4 v = make_uint4(0u, 0u, 0u, 0u);
        if (node < N_NODES) v = *(const uint4*)&hb[(size_t)node * D + ch * 8];
        *(uint4*)&zt[row * ZP + ch * 8] = v;
    }

    // gather-max: 16-lane group per node, MLP=8, tail-free (8-padded CSR)
    {
        int chunk = lane & 15;            // feats chunk*8..+7
        int sub   = lane >> 4;            // node-sub within wave
        #pragma unroll
        for (int g = 0; g < 4; g++){
            int ml = wv * 16 + g * 4 + sub;   // local node 0..63
            int node = nb + ml;
            int n = 0, base = 0;
            if (node < N_NODES){ n = deg[node]; base = off[node]; }
            const float NEG = -INFINITY;
            float a[8] = {NEG, NEG, NEG, NEG, NEG, NEG, NEG, NEG};
            int n8 = (n + 7) & ~7;            // 0 when n==0
            for (int i = 0; i < n8; i += 8){
                uint4 ss = *(const uint4*)&csr16[base + i];   // 8 edge ids, 16B-aligned
                int s0 = ss.x & 0xffff, s1 = ss.x >> 16;
                int s2 = ss.y & 0xffff, s3 = ss.y >> 16;
                int s4 = ss.z & 0xffff, s5 = ss.z >> 16;
                int s6 = ss.w & 0xffff, s7 = ss.w >> 16;
                uint4 v0 = *(const uint4*)&hb[(size_t)s0 * D + chunk * 8];
                uint4 v1 = *(const uint4*)&hb[(size_t)s1 * D + chunk * 8];
                uint4 v2 = *(const uint4*)&hb[(size_t)s2 * D + chunk * 8];
                uint4 v3 = *(const uint4*)&hb[(size_t)s3 * D + chunk * 8];
                uint4 v4 = *(const uint4*)&hb[(size_t)s4 * D + chunk * 8];
                uint4 v5 = *(const uint4*)&hb[(size_t)s5 * D + chunk * 8];
                uint4 v6 = *(const uint4*)&hb[(size_t)s6 * D + chunk * 8];
                uint4 v7 = *(const uint4*)&hb[(size_t)s7 * D + chunk * 8];
                maxbf8(a, v0); maxbf8(a, v1); maxbf8(a, v2); maxbf8(a, v3);
                maxbf8(a, v4); maxbf8(a, v5); maxbf8(a, v6); maxbf8(a, v7);
            }
            uint4 r;
            if (n == 0){
                r = make_uint4(0u, 0u, 0u, 0u);
            } else {
                r.x = pk2(a[0], a[1]); r.y = pk2(a[2], a[3]);
                r.z = pk2(a[4], a[5]); r.w = pk2(a[6], a[7]);
            }
            *(uint4*)&zt[ml * ZP + D + chunk * 8] = r;
        }
    }
    __syncthreads();

    // MFMA: 16 nodes x 128 outputs per wave
    int col = lane & 15;
    int quad = lane >> 4;
    int m0 = wv * 16;

    f32x4 acc[8];
    #pragma unroll
    for (int nt = 0; nt < 8; nt++) acc[nt] = (f32x4){0.f, 0.f, 0.f, 0.f};

    const unsigned short* zrow = &zt[(m0 + col) * ZP + quad * 8];
    const unsigned short* wrow = &Wt[(size_t)col * 256 + quad * 8];

    #pragma unroll
    for (int ks = 0; ks < 8; ks++){
        bf16x8 afrag = *(const bf16x8*)&zrow[ks * 32];
        #pragma unroll
        for (int nt = 0; nt < 8; nt++){
            bf16x8 bfrag = *(const bf16x8*)&wrow[nt * 16 * 256 + ks * 32];
            acc[nt] = __builtin_amdgcn_mfma_f32_16x16x32_bf16(afrag, bfrag, acc[nt], 0, 0, 0);
        }
    }

    // epilogue: C/D mapping col=lane&15, row=quad*4+reg; f32 out + bf16 shadow via LDS
    float yv[8][4];
    #pragma unroll
    for (int nt = 0; nt < 8; nt++){
        int feat = nt * 16 + col;
        float bb_ = b[feat];
        #pragma unroll
        for (int r = 0; r < 4; r++){
            int node = nb + m0 + quad * 4 + r;
            float y = leaky(acc[nt][r] + bb_);
            if (node < N_NODES){
                if (add_skip) y += hin[(size_t)node * D + feat];
                hout[(size_t)node * D + feat] = y;
            }
            yv[nt][r] = y;
        }
    }

    if (write_hb){
        __syncthreads();   // all MFMA reads of zt done
        #pragma unroll
        for (int nt = 0; nt < 8; nt++){
            int feat = nt * 16 + col;
            #pragma unroll
            for (int r = 0; r < 4; r++){
                int ml = m0 + quad * 4 + r;
                zt[ml * ZP + feat] = f2bf(yv[nt][r]);
            }
        }
        __syncthreads();
        #pragma unroll
        for (int j = 0; j < 4; j++){
            int idx = j * 256 + tid;
            int row = idx >> 4;
            int ch  = idx & 15;
            int node = nb + row;
            if (node < N_NODES)
                *(uint4*)&hbout[(size_t)node * D + ch * 8] = *(const uint4*)&zt[row * ZP + ch * 8];
        }
    }
}

// ---------------- global max-pool per graph (batch sorted, int32) ----------------
__global__ __launch_bounds__(256) void k_pool(const float* __restrict__ h, const int* __restrict__ batch,
                                              unsigned* __restrict__ xg){
    __shared__ unsigned lmax[2 * D];
    int tid = threadIdx.x;
    lmax[tid] = 0u;
    __syncthreads();

    int n0 = blockIdx.x * PBLK;
    int g0 = batch[n0];
    int q = tid & 31;
    int s = tid >> 5;
    int i0 = n0 + s * PSL;
    int i1 = min(i0 + PSL, N_NODES);

    if (i0 < N_NODES){
        const float NEG = -INFINITY;
        float4 m = make_float4(NEG, NEG, NEG, NEG);
        int curg = batch[i0];
        int i = i0;
        for (; i + 2 <= i1; i += 2){
            int ga = batch[i];
            int gb = batch[i + 1];
            float4 va = *(const float4*)&h[(size_t)i * D + 4 * q];
            float4 vb = *(const float4*)&h[(size_t)(i + 1) * D + 4 * q];
            if (ga != curg){
                int rel = curg - g0;
                unsigned* dst = (rel < 2) ? &lmax[rel * D + 4 * q] : &xg[curg * D + 4 * q];
                atomicMax(dst + 0, fenc(m.x)); atomicMax(dst + 1, fenc(m.y));
                atomicMax(dst + 2, fenc(m.z)); atomicMax(dst + 3, fenc(m.w));
                curg = ga; m = make_float4(NEG, NEG, NEG, NEG);
            }
            m = max4(m, va);
            if (gb != curg){
                int rel = curg - g0;
                unsigned* dst = (rel < 2) ? &lmax[rel * D + 4 * q] : &xg[curg * D + 4 * q];
                atomicMax(dst + 0, fenc(m.x)); atomicMax(dst + 1, fenc(m.y));
                atomicMax(dst + 2, fenc(m.z)); atomicMax(dst + 3, fenc(m.w));
                curg = gb; m = make_float4(NEG, NEG, NEG, NEG);
            }
            m = max4(m, vb);
        }
        if (i < i1){
            int ga = batch[i];
            float4 va = *(const float4*)&h[(size_t)i * D + 4 * q];
            if (ga != curg){
                int rel = curg - g0;
                unsigned* dst = (rel < 2) ? &lmax[rel * D + 4 * q] : &xg[curg * D + 4 * q];
                atomicMax(dst + 0, fenc(m.x)); atomicMax(dst + 1, fenc(m.y));
                atomicMax(dst + 2, fenc(m.z)); atomicMax(dst + 3, fenc(m.w));
                curg = ga; m = make_float4(NEG, NEG, NEG, NEG);
            }
            m = max4(m, va);
        }
        {
            int rel = curg - g0;
            unsigned* dst = (rel < 2) ? &lmax[rel * D + 4 * q] : &xg[curg * D + 4 * q];
            atomicMax(dst + 0, fenc(m.x)); atomicMax(dst + 1, fenc(m.y));
            atomicMax(dst + 2, fenc(m.z)); atomicMax(dst + 3, fenc(m.w));
        }
    }
    __syncthreads();

    if (tid < D){
        unsigned e = lmax[tid];
        if (e) atomicMax(&xg[g0 * D + tid], e);
    } else {
        int f = tid - D;
        int g1 = g0 + 1;
        if (g1 < N_GRAPHS){
            unsigned e = lmax[D + f];
            if (e) atomicMax(&xg[g1 * D + f], e);
        }
    }
}

// ---------------- head: leaky(xg @ wg[:128] + bg) ----------------
__global__ __launch_bounds__(256) void k_final(const unsigned* __restrict__ xg_enc, const float* __restrict__ wg,
                                               const float* __restrict__ bg, float* __restrict__ out){
    __shared__ float xs[N_GRAPHS * D];
    int tid = threadIdx.x;
    for (int i = tid; i < N_GRAPHS * D; i += 256){
        unsigned e = xg_enc[i];
        xs[i] = (e == 0u) ? 0.f : fdec(e);
    }
    __syncthreads();
    int g = tid >> 4;
    int j0 = (tid & 15) * 8;
    float acc[8];
    #pragma unroll
    for (int j = 0; j < 8; j++) acc[j] = 0.f;
    for (int k = 0; k < D; k++){
        float xv = xs[g * D + k];
        const float* wr = &wg[(size_t)k * D + j0];
        #pragma unroll
        for (int j = 0; j < 8; j++) acc[j] = fmaf(xv, wr[j], acc[j]);
    }
    float* orow = &out[(size_t)N_NODES * D + g * D + j0];
    #pragma unroll
    for (int j = 0; j < 8; j++) orow[j] = leaky(acc[j] + bg[j0 + j]);
}

extern "C" void kernel_launch(void* const* d_in, const int* in_sizes, int n_in,
                              void* d_out, int out_size, void* d_ws, size_t ws_size,
                              hipStream_t stream){
    const float* x = (const float*)d_in[0];
    const int* eidx  = (const int*)d_in[1];   // harness converts integer inputs to int32
    const int* batch = (const int*)d_in[2];
    const float* w[4]  = {(const float*)d_in[4], (const float*)d_in[6], (const float*)d_in[8], (const float*)d_in[10]};
    const float* bb[4] = {(const float*)d_in[5], (const float*)d_in[7], (const float*)d_in[9], (const float*)d_in[11]};
    const float* wg = (const float*)d_in[12];
    const float* bg = (const float*)d_in[13];
    const int* esrc = eidx;
    const int* edst = eidx + N_EDGES;

    // workspace layout (~16.0 MB)
    char* ws = (char*)d_ws;
    int* deg    = (int*)ws;       ws += 50048 * 4;
    int* off    = (int*)ws;       ws += 50048 * 4;
    int* cursor = (int*)ws;       ws += 50048 * 4;
    int* bsum   = (int*)ws;       ws += 256 * 4;
    int* bbase  = (int*)ws;       ws += 256 * 4;
    unsigned* xg_enc = (unsigned*)ws; ws += N_GRAPHS * D * 4;
    unsigned short* Wt = (unsigned short*)ws; ws += 4 * 2 * D * D * 2;  // 4 layers, [n][k] bf16
    unsigned short* csr16 = (unsigned short*)ws; ws += CSR_CAP * 2;
    unsigned short* hb = (unsigned short*)(((uintptr_t)ws + 255) & ~(uintptr_t)255); // 12.8 MB bf16 shadow
    float* h    = (float*)d_out;   // f32 h lives in the output buffer (fully written by step 0)

    k_pre  <<<6250, 256, 0, stream>>>(x, hb, w[0], w[1], w[2], w[3], Wt, deg, xg_enc);
    k_hist <<<(N_EDGES / 4 + 255) / 256, 256, 0, stream>>>(edst, deg);
    k_scan1<<<SCAN_BLOCKS, 256, 0, stream>>>(deg, bsum);
    k_scan2<<<1, 256, 0, stream>>>(bsum, bbase);
    k_scan3<<<SCAN_BLOCKS, 256, 0, stream>>>(deg, bbase, off, cursor);
    k_fill <<<(N_EDGES / 4 + 255) / 256, 256, 0, stream>>>(esrc, edst, cursor, csr16);
    k_pad  <<<SCAN_BLOCKS, 256, 0, stream>>>(deg, off, csr16);

    for (int s = 0; s < 4; s++){
        k_step<<<(N_NODES + 63) / 64, 256, 0, stream>>>(h, hb, csr16, deg, off,
                                                        Wt + (size_t)s * 2 * D * D, bb[s], h, hb,
                                                        s > 0, s < 3);
    }

    k_pool <<<(N_NODES + PBLK - 1) / PBLK, 256, 0, stream>>>(h, batch, xg_enc);
    k_final<<<1, 256, 0, stream>>>(xg_enc, wg, bg, (float*)d_out);
}

// Round 9
// 455.540 us; speedup vs baseline: 1.8825x; 1.0430x over previous
//
#include <hip/hip_runtime.h>
#include <stdint.h>
#include <math.h>

#define N_NODES 50000
#define N_EDGES 800000
#define D 128
#define N_GRAPHS 16
#define ZP 264         // LDS z-tile row pitch in bf16 elems (264*2B=528B -> 16B-aligned rows)
#define PBLK 128       // nodes per pool block
#define PSL 16         // nodes per pool slice
#define SCAN_BLOCKS 196
#define CSR_CAP 1150400 // sum of 8-padded degrees <= 800000 + 7*50000
#define HB_ELEMS ((size_t)N_NODES * D)

typedef __attribute__((ext_vector_type(8))) short bf16x8;   // 8 bf16 (4 VGPRs)
typedef __attribute__((ext_vector_type(4))) float f32x4;

__device__ __forceinline__ float leaky(float y){ return y > 0.f ? y : 0.01f * y; }

// monotonic float->uint encoding for atomic max; 0 = "empty" marker
__device__ __forceinline__ unsigned fenc(float f){
    unsigned u = __float_as_uint(f);
    return (f >= 0.f) ? (u | 0x80000000u) : ~u;
}
__device__ __forceinline__ float fdec(unsigned e){
    return (e & 0x80000000u) ? __uint_as_float(e & 0x7fffffffu) : __uint_as_float(~e);
}

// bf16 pack/unpack (round-to-nearest-even)
__device__ __forceinline__ unsigned short f2bf(float f){
    unsigned u = __float_as_uint(f);
    u += 0x7fffu + ((u >> 16) & 1u);
    return (unsigned short)(u >> 16);
}
__device__ __forceinline__ unsigned pk2(float lo, float hi){
    return (unsigned)f2bf(lo) | ((unsigned)f2bf(hi) << 16);
}
__device__ __forceinline__ void maxbf8(float a[8], uint4 v){
    a[0] = fmaxf(a[0], __uint_as_float(v.x << 16)); a[1] = fmaxf(a[1], __uint_as_float(v.x & 0xffff0000u));
    a[2] = fmaxf(a[2], __uint_as_float(v.y << 16)); a[3] = fmaxf(a[3], __uint_as_float(v.y & 0xffff0000u));
    a[4] = fmaxf(a[4], __uint_as_float(v.z << 16)); a[5] = fmaxf(a[5], __uint_as_float(v.z & 0xffff0000u));
    a[6] = fmaxf(a[6], __uint_as_float(v.w << 16)); a[7] = fmaxf(a[7], __uint_as_float(v.w & 0xffff0000u));
}
__device__ __forceinline__ float4 max4(float4 a, float4 b){
    float4 r;
    r.x = fmaxf(a.x, b.x); r.y = fmaxf(a.y, b.y);
    r.z = fmaxf(a.z, b.z); r.w = fmaxf(a.w, b.w);
    return r;
}

// ---------------- combined pre-pass: hb=bf16(x), Wt transpose, zero deg/xg ----------------
__global__ __launch_bounds__(256) void k_pre(const float* __restrict__ x, unsigned short* __restrict__ hb,
                                             const float* __restrict__ w0, const float* __restrict__ w1,
                                             const float* __restrict__ w2, const float* __restrict__ w3,
                                             unsigned short* __restrict__ Wt,
                                             int* __restrict__ deg, unsigned* __restrict__ xg){
    int id = blockIdx.x * 256 + threadIdx.x;
    if (id < N_NODES * D / 4){
        float4 v = ((const float4*)x)[id];
        uint2 r; r.x = pk2(v.x, v.y); r.y = pk2(v.z, v.w);
        ((uint2*)hb)[id] = r;
    }
    if (id < 4 * D * 2 * D){
        int layer = id >> 15;
        int rem = id & 32767;
        int n = rem >> 8;
        int k = rem & 255;
        const float* w = (layer == 0) ? w0 : (layer == 1) ? w1 : (layer == 2) ? w2 : w3;
        Wt[id] = f2bf(w[(size_t)k * D + n]);
    }
    if (id < 50048) deg[id] = 0;
    if (id < N_GRAPHS * D) xg[id] = 0u;
}

// ---------------- f32 -> bf16 shadow convert (fallback path, race-free across launches) ------------
__global__ __launch_bounds__(256) void k_cvt(const float* __restrict__ src, unsigned short* __restrict__ dst){
    int id = blockIdx.x * 256 + threadIdx.x;
    if (id < N_NODES * D / 4){
        float4 v = ((const float4*)src)[id];
        uint2 r; r.x = pk2(v.x, v.y); r.y = pk2(v.z, v.w);
        ((uint2*)dst)[id] = r;
    }
}

// ---------------- CSR build (int4 reads, ushort entries, 8-aligned 8-padded segments) ----------------
__global__ __launch_bounds__(256) void k_hist(const int* __restrict__ dst, int* __restrict__ deg){
    int e4 = blockIdx.x * 256 + threadIdx.x;
    if (e4 < N_EDGES / 4){
        int4 d = ((const int4*)dst)[e4];
        atomicAdd(&deg[d.x], 1); atomicAdd(&deg[d.y], 1);
        atomicAdd(&deg[d.z], 1); atomicAdd(&deg[d.w], 1);
    }
}

__global__ __launch_bounds__(256) void k_scan1(const int* __restrict__ deg, int* __restrict__ bsum){
    __shared__ int sh[256];
    int i = blockIdx.x * 256 + threadIdx.x;
    int dv = (i < N_NODES) ? deg[i] : 0;
    sh[threadIdx.x] = (dv + 7) & ~7;               // 8-padded
    __syncthreads();
    for (int s = 128; s > 0; s >>= 1){
        if (threadIdx.x < s) sh[threadIdx.x] += sh[threadIdx.x + s];
        __syncthreads();
    }
    if (threadIdx.x == 0) bsum[blockIdx.x] = sh[0];
}

__global__ __launch_bounds__(256) void k_scan2(const int* __restrict__ bsum, int* __restrict__ bbase){
    __shared__ int sh[256];
    int t = threadIdx.x;
    int v = (t < SCAN_BLOCKS) ? bsum[t] : 0;
    sh[t] = v;
    __syncthreads();
    for (int d = 1; d < 256; d <<= 1){
        int tv = (t >= d) ? sh[t - d] : 0;
        __syncthreads();
        sh[t] += tv;
        __syncthreads();
    }
    if (t < SCAN_BLOCKS) bbase[t] = sh[t] - v;   // exclusive
}

__global__ __launch_bounds__(256) void k_scan3(const int* __restrict__ deg, const int* __restrict__ bbase,
                                               int* __restrict__ off, int* __restrict__ cursor){
    __shared__ int sh[256];
    int t = threadIdx.x;
    int i = blockIdx.x * 256 + t;
    int dv = (i < N_NODES) ? deg[i] : 0;
    int v = (dv + 7) & ~7;                        // 8-padded
    sh[t] = v;
    __syncthreads();
    for (int d = 1; d < 256; d <<= 1){
        int tv = (t >= d) ? sh[t - d] : 0;
        __syncthreads();
        sh[t] += tv;
        __syncthreads();
    }
    if (i < N_NODES){
        int e = bbase[blockIdx.x] + sh[t] - v;    // 8-aligned base
        off[i] = e;
        cursor[i] = e;
    }
}

__global__ __launch_bounds__(256) void k_fill(const int* __restrict__ src, const int* __restrict__ dst,
                                              int* __restrict__ cursor, unsigned short* __restrict__ csr16){
    int e4 = blockIdx.x * 256 + threadIdx.x;
    if (e4 < N_EDGES / 4){
        int4 d = ((const int4*)dst)[e4];
        int4 s = ((const int4*)src)[e4];
        int p;
        p = atomicAdd(&cursor[d.x], 1); csr16[p] = (unsigned short)s.x;
        p = atomicAdd(&cursor[d.y], 1); csr16[p] = (unsigned short)s.y;
        p = atomicAdd(&cursor[d.z], 1); csr16[p] = (unsigned short)s.z;
        p = atomicAdd(&cursor[d.w], 1); csr16[p] = (unsigned short)s.w;
    }
}

// pad each node's segment to a multiple of 8 by duplicating its first edge (max-invariant)
__global__ __launch_bounds__(256) void k_pad(const int* __restrict__ deg, const int* __restrict__ off,
                                             unsigned short* __restrict__ csr16){
    int i = blockIdx.x * 256 + threadIdx.x;
    if (i < N_NODES){
        int n = deg[i];
        if (n > 0){
            int base = off[i];
            unsigned short s0 = csr16[base];
            int n8 = (n + 7) & ~7;
            for (int j = n; j < n8; j++) csr16[base + j] = s0;
        }
    }
}

// ---------------- fused step: agg-gather (bf16, MLP=8) + MFMA GEMM + leaky + skip + hb_nxt write ---
// block = 64 nodes, 512 threads (8 waves). MFMA: wave w owns node-group (w&3)*16 and output-half (w>>2)*64.
// READS hb_in, WRITES hb_out (different buffer when ping-pong active -> no cross-block race).
__global__ __launch_bounds__(512, 8) void k_step(const float* __restrict__ hin,
                                              const unsigned short* __restrict__ hb,
                                              const unsigned short* __restrict__ csr16,
                                              const int* __restrict__ deg, const int* __restrict__ off,
                                              const unsigned short* __restrict__ Wt, const float* __restrict__ b,
                                              float* __restrict__ hout, unsigned short* __restrict__ hbout,
                                              int add_skip, int write_hb){
    __shared__ unsigned short zt[64 * ZP];
    int tid = threadIdx.x;
    int nb = blockIdx.x * 64;
    int lane = tid & 63;
    int wv = tid >> 6;                    // 0..7

    // stage h-half (coalesced 16B chunks): 1024 slots, 512 threads x 2
    #pragma unroll
    for (int j = 0; j < 2; j++){
        int idx = j * 512 + tid;          // 0..1023
        int row = idx >> 4;               // 0..63
        int ch  = idx & 15;               // 16B chunk -> feats ch*8..+7
        int node = nb + row;
        uint4 v = make_uint4(0u, 0u, 0u, 0u);
        if (node < N_NODES) v = *(const uint4*)&hb[(size_t)node * D + ch * 8];
        *(uint4*)&zt[row * ZP + ch * 8] = v;
    }

    // gather-max: 32 16-lane groups, 2 nodes each, MLP=8, tail-free (8-padded CSR)
    {
        int group = tid >> 4;             // 0..31
        int chunk = tid & 15;             // feats chunk*8..+7
        #pragma unroll
        for (int g = 0; g < 2; g++){
            int ml = group + g * 32;      // local node 0..63
            int node = nb + ml;
            int n = 0, base = 0;
            if (node < N_NODES){ n = deg[node]; base = off[node]; }
            const float NEG = -INFINITY;
            float a[8] = {NEG, NEG, NEG, NEG, NEG, NEG, NEG, NEG};
            int n8 = (n + 7) & ~7;        // 0 when n==0
            for (int i = 0; i < n8; i += 8){
                uint4 ss = *(const uint4*)&csr16[base + i];   // 8 edge ids, 16B-aligned
                int s0 = ss.x & 0xffff, s1 = ss.x >> 16;
                int s2 = ss.y & 0xffff, s3 = ss.y >> 16;
                int s4 = ss.z & 0xffff, s5 = ss.z >> 16;
                int s6 = ss.w & 0xffff, s7 = ss.w >> 16;
                uint4 v0 = *(const uint4*)&hb[(size_t)s0 * D + chunk * 8];
                uint4 v1 = *(const uint4*)&hb[(size_t)s1 * D + chunk * 8];
                uint4 v2 = *(const uint4*)&hb[(size_t)s2 * D + chunk * 8];
                uint4 v3 = *(const uint4*)&hb[(size_t)s3 * D + chunk * 8];
                uint4 v4 = *(const uint4*)&hb[(size_t)s4 * D + chunk * 8];
                uint4 v5 = *(const uint4*)&hb[(size_t)s5 * D + chunk * 8];
                uint4 v6 = *(const uint4*)&hb[(size_t)s6 * D + chunk * 8];
                uint4 v7 = *(const uint4*)&hb[(size_t)s7 * D + chunk * 8];
                maxbf8(a, v0); maxbf8(a, v1); maxbf8(a, v2); maxbf8(a, v3);
                maxbf8(a, v4); maxbf8(a, v5); maxbf8(a, v6); maxbf8(a, v7);
            }
            uint4 r;
            if (n == 0){
                r = make_uint4(0u, 0u, 0u, 0u);
            } else {
                r.x = pk2(a[0], a[1]); r.y = pk2(a[2], a[3]);
                r.z = pk2(a[4], a[5]); r.w = pk2(a[6], a[7]);
            }
            *(uint4*)&zt[ml * ZP + D + chunk * 8] = r;
        }
    }
    __syncthreads();

    // MFMA: wave w -> nodes (w&3)*16..+15, output-half (w>>2)*64..+63
    int col = lane & 15;
    int quad = lane >> 4;
    int mg = wv & 3;
    int og = wv >> 2;
    int m0 = mg * 16;
    int f0 = og * 64;

    f32x4 acc[4];
    #pragma unroll
    for (int nt = 0; nt < 4; nt++) acc[nt] = (f32x4){0.f, 0.f, 0.f, 0.f};

    const unsigned short* zrow = &zt[(m0 + col) * ZP + quad * 8];
    const unsigned short* wrow = &Wt[(size_t)(f0 + col) * 256 + quad * 8];

    #pragma unroll
    for (int ks = 0; ks < 8; ks++){
        bf16x8 afrag = *(const bf16x8*)&zrow[ks * 32];
        #pragma unroll
        for (int nt = 0; nt < 4; nt++){
            bf16x8 bfrag = *(const bf16x8*)&wrow[nt * 16 * 256 + ks * 32];
            acc[nt] = __builtin_amdgcn_mfma_f32_16x16x32_bf16(afrag, bfrag, acc[nt], 0, 0, 0);
        }
    }

    // epilogue: C/D mapping col=lane&15, row=quad*4+reg; f32 out (+skip), bf16 shadow via LDS
    float yv[4][4];
    #pragma unroll
    for (int nt = 0; nt < 4; nt++){
        int feat = f0 + nt * 16 + col;
        float bb_ = b[feat];
        #pragma unroll
        for (int r = 0; r < 4; r++){
            int node = nb + m0 + quad * 4 + r;
            float y = leaky(acc[nt][r] + bb_);
            if (node < N_NODES){
                if (add_skip) y += hin[(size_t)node * D + feat];
                hout[(size_t)node * D + feat] = y;
            }
            yv[nt][r] = y;
        }
    }

    if (write_hb){
        __syncthreads();   // all MFMA reads of zt done
        #pragma unroll
        for (int nt = 0; nt < 4; nt++){
            int feat = f0 + nt * 16 + col;
            #pragma unroll
            for (int r = 0; r < 4; r++){
                int ml = m0 + quad * 4 + r;
                zt[ml * ZP + feat] = f2bf(yv[nt][r]);
            }
        }
        __syncthreads();
        #pragma unroll
        for (int j = 0; j < 2; j++){
            int idx = j * 512 + tid;
            int row = idx >> 4;
            int ch  = idx & 15;
            int node = nb + row;
            if (node < N_NODES)
                *(uint4*)&hbout[(size_t)node * D + ch * 8] = *(const uint4*)&zt[row * ZP + ch * 8];
        }
    }
}

// ---------------- global max-pool per graph (batch sorted, int32) ----------------
__global__ __launch_bounds__(256) void k_pool(const float* __restrict__ h, const int* __restrict__ batch,
                                              unsigned* __restrict__ xg){
    __shared__ unsigned lmax[2 * D];
    int tid = threadIdx.x;
    lmax[tid] = 0u;
    __syncthreads();

    int n0 = blockIdx.x * PBLK;
    int g0 = batch[n0];
    int q = tid & 31;
    int s = tid >> 5;
    int i0 = n0 + s * PSL;
    int i1 = min(i0 + PSL, N_NODES);

    if (i0 < N_NODES){
        const float NEG = -INFINITY;
        float4 m = make_float4(NEG, NEG, NEG, NEG);
        int curg = batch[i0];
        int i = i0;
        for (; i + 2 <= i1; i += 2){
            int ga = batch[i];
            int gb = batch[i + 1];
            float4 va = *(const float4*)&h[(size_t)i * D + 4 * q];
            float4 vb = *(const float4*)&h[(size_t)(i + 1) * D + 4 * q];
            if (ga != curg){
                int rel = curg - g0;
                unsigned* dst = (rel < 2) ? &lmax[rel * D + 4 * q] : &xg[curg * D + 4 * q];
                atomicMax(dst + 0, fenc(m.x)); atomicMax(dst + 1, fenc(m.y));
                atomicMax(dst + 2, fenc(m.z)); atomicMax(dst + 3, fenc(m.w));
                curg = ga; m = make_float4(NEG, NEG, NEG, NEG);
            }
            m = max4(m, va);
            if (gb != curg){
                int rel = curg - g0;
                unsigned* dst = (rel < 2) ? &lmax[rel * D + 4 * q] : &xg[curg * D + 4 * q];
                atomicMax(dst + 0, fenc(m.x)); atomicMax(dst + 1, fenc(m.y));
                atomicMax(dst + 2, fenc(m.z)); atomicMax(dst + 3, fenc(m.w));
                curg = gb; m = make_float4(NEG, NEG, NEG, NEG);
            }
            m = max4(m, vb);
        }
        if (i < i1){
            int ga = batch[i];
            float4 va = *(const float4*)&h[(size_t)i * D + 4 * q];
            if (ga != curg){
                int rel = curg - g0;
                unsigned* dst = (rel < 2) ? &lmax[rel * D + 4 * q] : &xg[curg * D + 4 * q];
                atomicMax(dst + 0, fenc(m.x)); atomicMax(dst + 1, fenc(m.y));
                atomicMax(dst + 2, fenc(m.z)); atomicMax(dst + 3, fenc(m.w));
                curg = ga; m = make_float4(NEG, NEG, NEG, NEG);
            }
            m = max4(m, va);
        }
        {
            int rel = curg - g0;
            unsigned* dst = (rel < 2) ? &lmax[rel * D + 4 * q] : &xg[curg * D + 4 * q];
            atomicMax(dst + 0, fenc(m.x)); atomicMax(dst + 1, fenc(m.y));
            atomicMax(dst + 2, fenc(m.z)); atomicMax(dst + 3, fenc(m.w));
        }
    }
    __syncthreads();

    if (tid < D){
        unsigned e = lmax[tid];
        if (e) atomicMax(&xg[g0 * D + tid], e);
    } else {
        int f = tid - D;
        int g1 = g0 + 1;
        if (g1 < N_GRAPHS){
            unsigned e = lmax[D + f];
            if (e) atomicMax(&xg[g1 * D + f], e);
        }
    }
}

// ---------------- head: leaky(xg @ wg[:128] + bg) ----------------
__global__ __launch_bounds__(256) void k_final(const unsigned* __restrict__ xg_enc, const float* __restrict__ wg,
                                               const float* __restrict__ bg, float* __restrict__ out){
    __shared__ float xs[N_GRAPHS * D];
    int tid = threadIdx.x;
    for (int i = tid; i < N_GRAPHS * D; i += 256){
        unsigned e = xg_enc[i];
        xs[i] = (e == 0u) ? 0.f : fdec(e);
    }
    __syncthreads();
    int g = tid >> 4;
    int j0 = (tid & 15) * 8;
    float acc[8];
    #pragma unroll
    for (int j = 0; j < 8; j++) acc[j] = 0.f;
    for (int k = 0; k < D; k++){
        float xv = xs[g * D + k];
        const float* wr = &wg[(size_t)k * D + j0];
        #pragma unroll
        for (int j = 0; j < 8; j++) acc[j] = fmaf(xv, wr[j], acc[j]);
    }
    float* orow = &out[(size_t)N_NODES * D + g * D + j0];
    #pragma unroll
    for (int j = 0; j < 8; j++) orow[j] = leaky(acc[j] + bg[j0 + j]);
}

extern "C" void kernel_launch(void* const* d_in, const int* in_sizes, int n_in,
                              void* d_out, int out_size, void* d_ws, size_t ws_size,
                              hipStream_t stream){
    const float* x = (const float*)d_in[0];
    const int* eidx  = (const int*)d_in[1];   // harness converts integer inputs to int32
    const int* batch = (const int*)d_in[2];
    const float* w[4]  = {(const float*)d_in[4], (const float*)d_in[6], (const float*)d_in[8], (const float*)d_in[10]};
    const float* bb[4] = {(const float*)d_in[5], (const float*)d_in[7], (const float*)d_in[9], (const float*)d_in[11]};
    const float* wg = (const float*)d_in[12];
    const float* bg = (const float*)d_in[13];
    const int* esrc = eidx;
    const int* edst = eidx + N_EDGES;

    // workspace layout: base ~3.4 MB + hb0 12.8 MB (+ hb1 12.8 MB if ws allows ping-pong)
    char* ws = (char*)d_ws;
    int* deg    = (int*)ws;       ws += 50048 * 4;
    int* off    = (int*)ws;       ws += 50048 * 4;
    int* cursor = (int*)ws;       ws += 50048 * 4;
    int* bsum   = (int*)ws;       ws += 256 * 4;
    int* bbase  = (int*)ws;       ws += 256 * 4;
    unsigned* xg_enc = (unsigned*)ws; ws += N_GRAPHS * D * 4;
    unsigned short* Wt = (unsigned short*)ws; ws += 4 * 2 * D * D * 2;  // 4 layers, [n][k] bf16
    unsigned short* csr16 = (unsigned short*)ws; ws += CSR_CAP * 2;
    unsigned short* hb0 = (unsigned short*)(((uintptr_t)ws + 255) & ~(uintptr_t)255);
    unsigned short* hb1 = hb0 + HB_ELEMS;
    size_t need_pp = (size_t)((char*)(hb1 + HB_ELEMS) - (char*)d_ws);
    int pp = (ws_size >= need_pp);     // ping-pong shadow if workspace allows (deterministic per run)
    float* h = (float*)d_out;          // f32 h lives in the output buffer (fully written by step 0)

    k_pre  <<<6250, 256, 0, stream>>>(x, hb0, w[0], w[1], w[2], w[3], Wt, deg, xg_enc);
    k_hist <<<(N_EDGES / 4 + 255) / 256, 256, 0, stream>>>(edst, deg);
    k_scan1<<<SCAN_BLOCKS, 256, 0, stream>>>(deg, bsum);
    k_scan2<<<1, 256, 0, stream>>>(bsum, bbase);
    k_scan3<<<SCAN_BLOCKS, 256, 0, stream>>>(deg, bbase, off, cursor);
    k_fill <<<(N_EDGES / 4 + 255) / 256, 256, 0, stream>>>(esrc, edst, cursor, csr16);
    k_pad  <<<SCAN_BLOCKS, 256, 0, stream>>>(deg, off, csr16);

    unsigned short* cur = hb0;
    unsigned short* nxt = pp ? hb1 : hb0;
    for (int s = 0; s < 4; s++){
        int wb = pp && (s < 3);        // ping-pong: write next shadow in-kernel (separate buffer)
        k_step<<<(N_NODES + 63) / 64, 512, 0, stream>>>(h, cur, csr16, deg, off,
                                                        Wt + (size_t)s * 2 * D * D, bb[s], h, nxt,
                                                        s > 0, wb);
        if (!pp && s < 3)              // fallback: refresh single shadow in a separate launch
            k_cvt<<<6250, 256, 0, stream>>>(h, hb0);
        if (pp){ unsigned short* t = cur; cur = nxt; nxt = t; }
    }

    k_pool <<<(N_NODES + PBLK - 1) / PBLK, 256, 0, stream>>>(h, batch, xg_enc);
    k_final<<<1, 256, 0, stream>>>(xg_enc, wg, bg, (float*)d_out);
}